// Round 1
// baseline (966.706 us; speedup 1.0000x reference)
//
#include <hip/hip_runtime.h>
#include <math.h>

typedef __attribute__((ext_vector_type(8))) short short8;
typedef __attribute__((ext_vector_type(4))) float f32x4;

static __device__ inline unsigned short f2bf(float f) {
    union { float f; unsigned u; } v; v.f = f;
    unsigned r = v.u + 0x7FFF + ((v.u >> 16) & 1);
    return (unsigned short)(r >> 16);
}

// ---------------- MFMA bf16 GEMM: C[M,N] = A[M,K] @ BT[N,K]^T + bias ----------------
// Block tile: 128 x (WJ*32), BK=64. 4 waves in 2x2. Wave tile: 64 x (WJ*16).
// GATHER: A row index comes from gidx[] (used to emit bpair in CSR order).
template<int WJ, bool GATHER>
__global__ __launch_bounds__(256) void gemm_mfma(
    const float* __restrict__ A, int lda,
    const int* __restrict__ gidx,
    const float* __restrict__ BT, int ldb,   // BT is [N][K] row-major
    const float* __restrict__ bias,
    float* __restrict__ C, int ldc,
    int M, int N, int K)
{
    constexpr int GBN = WJ * 32;
    __shared__ unsigned short As[128 * 72];
    __shared__ unsigned short Bs[GBN * 72];

    const int t = threadIdx.x;
    const int wid = t >> 6, lane = t & 63;
    const int wm = (wid & 1) * 64;
    const int wn = (wid >> 1) * (WJ * 16);
    const int row16 = lane & 15, quad = lane >> 4;
    const int bm = blockIdx.x * 128;
    const int bn = blockIdx.y * GBN;

    f32x4 acc[4][WJ];
    #pragma unroll
    for (int i = 0; i < 4; ++i)
        #pragma unroll
        for (int j = 0; j < WJ; ++j)
            #pragma unroll
            for (int r = 0; r < 4; ++r) acc[i][j][r] = 0.f;

    const int ktiles = (K + 63) >> 6;
    for (int kt = 0; kt < ktiles; ++kt) {
        const int k0 = kt << 6;
        // stage A: 128 rows x 64 k
        #pragma unroll
        for (int it = 0; it < 8; ++it) {
            int f = it * 256 + t;
            int row = f >> 4, kq = (f & 15) << 2;
            float4 av = make_float4(0.f, 0.f, 0.f, 0.f);
            if (bm + row < M && k0 + kq < K) {
                size_t ar;
                if constexpr (GATHER) ar = (size_t)gidx[bm + row];
                else                  ar = (size_t)(bm + row);
                av = *(const float4*)(A + ar * lda + k0 + kq);
            }
            ushort4 uv;
            uv.x = f2bf(av.x); uv.y = f2bf(av.y); uv.z = f2bf(av.z); uv.w = f2bf(av.w);
            *(ushort4*)(&As[row * 72 + kq]) = uv;
        }
        // stage B: GBN rows x 64 k
        #pragma unroll
        for (int it = 0; it < WJ * 2; ++it) {
            int f = it * 256 + t;
            int row = f >> 4, kq = (f & 15) << 2;
            float4 bv = make_float4(0.f, 0.f, 0.f, 0.f);
            if (bn + row < N && k0 + kq < K)
                bv = *(const float4*)(BT + (size_t)(bn + row) * ldb + k0 + kq);
            ushort4 uv;
            uv.x = f2bf(bv.x); uv.y = f2bf(bv.y); uv.z = f2bf(bv.z); uv.w = f2bf(bv.w);
            *(ushort4*)(&Bs[row * 72 + kq]) = uv;
        }
        __syncthreads();

        #pragma unroll
        for (int ks = 0; ks < 64; ks += 32) {
            short8 af[4], bfv[WJ];
            #pragma unroll
            for (int i = 0; i < 4; ++i)
                af[i] = *(const short8*)(&As[(wm + i * 16 + row16) * 72 + ks + quad * 8]);
            #pragma unroll
            for (int j = 0; j < WJ; ++j)
                bfv[j] = *(const short8*)(&Bs[(wn + j * 16 + row16) * 72 + ks + quad * 8]);
            #pragma unroll
            for (int i = 0; i < 4; ++i)
                #pragma unroll
                for (int j = 0; j < WJ; ++j)
                    acc[i][j] = __builtin_amdgcn_mfma_f32_16x16x32_bf16(af[i], bfv[j], acc[i][j], 0, 0, 0);
        }
        __syncthreads();
    }

    #pragma unroll
    for (int i = 0; i < 4; ++i)
        #pragma unroll
        for (int j = 0; j < WJ; ++j) {
            int col = bn + wn + j * 16 + row16;
            if (col >= N) continue;
            float bv = bias ? bias[col] : 0.f;
            #pragma unroll
            for (int r = 0; r < 4; ++r) {
                int row = bm + wm + i * 16 + quad * 4 + r;
                if (row < M) C[(size_t)row * ldc + col] = acc[i][j][r] + bv;
            }
        }
}

// ---------------- prep: transpose/concat weights, fold logit scales, zero cnt ----------------
__global__ void prep_kernel(const float* __restrict__ Wq, const float* __restrict__ bq,
                            const float* __restrict__ Wqp, const float* __restrict__ bqp,
                            const float* __restrict__ Wb, const float* __restrict__ bb,
                            const float* __restrict__ Wdz, const float* __restrict__ bdz,
                            const float* __restrict__ Wks, const float* __restrict__ Wout,
                            float* __restrict__ wqqpT, float* __restrict__ bqqp,
                            float* __restrict__ wcatT, float* __restrict__ bcat,
                            float* __restrict__ wksT, float* __restrict__ woutT,
                            int* __restrict__ cnt, int n)
{
    const float SC_QK = 0.14433756729740643f;   // sqrt(1/48), folded into q
    const float SC_B  = 0.5773502691896258f;    // sqrt(1/3), folded into b
    int gid = blockIdx.x * 256 + threadIdx.x;
    int stride = gridDim.x * 256;
    for (int i = gid; i < n; i += stride) cnt[i] = 0;
    for (int i = gid; i < 320 * 384; i += stride) {
        int o = i / 384, c = i % 384;
        wqqpT[i] = (o < 128) ? Wq[c * 128 + o] * SC_QK : Wqp[c * 192 + (o - 128)];
    }
    for (int i = gid; i < 320; i += stride) bqqp[i] = (i < 128) ? bq[i] * SC_QK : bqp[i - 128];
    for (int i = gid; i < 40 * 128; i += stride) {
        int o = i >> 7, c = i & 127;
        wcatT[i] = (o < 8) ? Wb[c * 8 + o] * SC_B : Wdz[c * 32 + (o - 8)];
    }
    for (int i = gid; i < 40; i += stride) bcat[i] = (i < 8) ? bb[i] * SC_B : bdz[i - 8];
    for (int i = gid; i < 128 * 128; i += stride) {
        int o = i >> 7, c = i & 127;
        wksT[i] = Wks[c * 128 + o];
    }
    for (int i = gid; i < 384 * 416; i += stride) {
        int o = i / 416, c = i % 416;
        woutT[i] = Wout[c * 384 + o];
    }
}

// ---------------- k_pts ----------------
__global__ void kpts_kernel(const float* __restrict__ tfn, const float* __restrict__ Wkv,
                            float* __restrict__ kpts, int n)
{
    int t = blockIdx.x * 256 + threadIdx.x;
    if (t >= n * 24) return;
    int node = t / 24, f = t % 24;
    int a = f >> 3;
    int b = f & 7;
    const float* vr = tfn + (size_t)node * 176 + 128;
    float s = 0.f;
    #pragma unroll
    for (int p = 0; p < 16; ++p) s += vr[p * 3 + a] * Wkv[p * 8 + b];
    kpts[t] = s;
}

// ---------------- q_pts rotation (qpraw has row stride 320, cols 128..319 of qqp) ----------------
__global__ void qpts_kernel(const float* __restrict__ qpraw, const float* __restrict__ rot,
                            const float* __restrict__ trans, float* __restrict__ qpts, int n)
{
    int t = blockIdx.x * 256 + threadIdx.x;
    if (t >= n * 64) return;
    int node = t / 64, hk = t % 64;
    const float* qr = qpraw + (size_t)node * 320;
    float r0 = qr[hk], r1 = qr[64 + hk], r2 = qr[128 + hk];
    const float* R = rot + (size_t)node * 9;
    const float* T = trans + (size_t)node * 3;
    float* o = qpts + (size_t)node * 192 + hk * 3;
    #pragma unroll
    for (int i = 0; i < 3; ++i)
        o[i] = R[i * 3 + 0] * r0 + R[i * 3 + 1] * r1 + R[i * 3 + 2] * r2 + T[i];
}

// ---------------- CSR build ----------------
__global__ void count_kernel(const int* __restrict__ srcA, int* __restrict__ cnt, int E)
{
    int e = blockIdx.x * 256 + threadIdx.x;
    if (e < E) atomicAdd(&cnt[srcA[e]], 1);
}

__global__ void scan_kernel(const int* __restrict__ cnt, int* __restrict__ off,
                            int* __restrict__ cur, int n)
{
    __shared__ int sums[1024];
    int t = threadIdx.x;
    int chunk = (n + 1023) >> 10;
    int begin = t * chunk;
    int local = 0;
    for (int j = 0; j < chunk; ++j) {
        int i = begin + j;
        if (i < n) local += cnt[i];
    }
    sums[t] = local;
    __syncthreads();
    for (int d = 1; d < 1024; d <<= 1) {
        int x = sums[t];
        int y = (t >= d) ? sums[t - d] : 0;
        __syncthreads();
        sums[t] = x + y;
        __syncthreads();
    }
    int run = sums[t] - local;
    for (int j = 0; j < chunk; ++j) {
        int i = begin + j;
        if (i < n) {
            off[i] = run;
            cur[i] = run;
            run += cnt[i];
        }
    }
}

// fill also gathers dst into CSR order so attn needs no indirection.
__global__ void fill_kernel(const int* __restrict__ srcA, const int* __restrict__ dstA,
                            int* __restrict__ cur, int* __restrict__ elist,
                            int* __restrict__ dsts, int E)
{
    int e = blockIdx.x * 256 + threadIdx.x;
    if (e < E) {
        int s = srcA[e];
        int pos = atomicAdd(&cur[s], 1);
        elist[pos] = e;
        dsts[pos] = dstA[e];
    }
}

// ---------------- attention + aggregation + finalize: one wave per src node ----------------
// lane = es*8 + h : es = edge slot (0..7), h = head (0..7)
// bpair and dsts are in CSR (elist) order -> sequential segment reads.
__global__ __launch_bounds__(256) void attn_kernel(
    const int* __restrict__ off, const int* __restrict__ cnt,
    const int* __restrict__ dsts,
    const float* __restrict__ qqp, const float* __restrict__ kbuf,
    const float* __restrict__ qpts, const float* __restrict__ kpts,
    const float* __restrict__ bpair, const float* __restrict__ mask,
    const float* __restrict__ hwin,
    const float* __restrict__ rot, const float* __restrict__ trans,
    float* __restrict__ feats, int n)
{
    int wave = threadIdx.x >> 6;
    int lane = threadIdx.x & 63;
    int s = blockIdx.x * 4 + wave;
    if (s >= n) return;
    int es = lane >> 3;
    int h  = lane & 7;

    float qh[16];
    {
        const float* qp = qqp + (size_t)s * 320 + h * 16;
        #pragma unroll
        for (int c = 0; c < 16; ++c) qh[c] = qp[c];
    }
    float qpt[24];
    {
        const float* pp = qpts + (size_t)s * 192 + h * 24;
        #pragma unroll
        for (int j = 0; j < 24; ++j) qpt[j] = pp[j];
    }
    // softplus(hw) * sqrt(1/108) * 0.5 folded together
    float hwv = log1pf(__expf(hwin[h])) * 0.04811252243246882f;
    float mask_s = mask[s];
    int myoff = off[s], mycnt = cnt[s];

    float ssum = 0.f;
    float oacc[16];
    #pragma unroll
    for (int c = 0; c < 16; ++c) oacc[c] = 0.f;
    float optacc[3] = {0.f, 0.f, 0.f};
    float opacc[8][4];
    #pragma unroll
    for (int j = 0; j < 8; ++j)
        #pragma unroll
        for (int c = 0; c < 4; ++c) opacc[j][c] = 0.f;

    int nb = (mycnt + 7) >> 3;
    for (int b = 0; b < nb; ++b) {
        int idx = b * 8 + es;
        bool valid = idx < mycnt;
        int pos = myoff + (valid ? idx : 0);
        int d = dsts[pos];

        const float* bp = bpair + (size_t)pos * 40;
        float bh = bp[h];
        float4 pair4 = *(const float4*)(bp + 8 + h * 4);

        const float* kr = kbuf + (size_t)d * 128 + h * 16;
        float4 ka = *(const float4*)(kr + 0);
        float4 kb = *(const float4*)(kr + 4);
        float4 kc = *(const float4*)(kr + 8);
        float4 kd = *(const float4*)(kr + 12);

        const float* kp = kpts + (size_t)d * 24 + h * 3;
        float kp0 = kp[0], kp1 = kp[1], kp2 = kp[2];

        float qk = qh[0] * ka.x + qh[1] * ka.y + qh[2] * ka.z + qh[3] * ka.w
                 + qh[4] * kb.x + qh[5] * kb.y + qh[6] * kb.z + qh[7] * kb.w
                 + qh[8] * kc.x + qh[9] * kc.y + qh[10] * kc.z + qh[11] * kc.w
                 + qh[12] * kd.x + qh[13] * kd.y + qh[14] * kd.z + qh[15] * kd.w;

        float pt = 0.f;
        #pragma unroll
        for (int pp = 0; pp < 8; ++pp) {
            float d0 = qpt[pp * 3 + 0] - kp0;
            float d1 = qpt[pp * 3 + 1] - kp1;
            float d2 = qpt[pp * 3 + 2] - kp2;
            pt += d0 * d0 + d1 * d1 + d2 * d2;
        }

        float md = mask[d];
        // qk and bh arrive pre-scaled (folded into weights at prep)
        float logit = qk + bh - hwv * pt + 100000.0f * (mask_s * md - 1.0f);
        float w = valid ? __expf(logit) : 0.f;

        ssum += w;
        oacc[0] += w * ka.x; oacc[1] += w * ka.y; oacc[2] += w * ka.z; oacc[3] += w * ka.w;
        oacc[4] += w * kb.x; oacc[5] += w * kb.y; oacc[6] += w * kb.z; oacc[7] += w * kb.w;
        oacc[8] += w * kc.x; oacc[9] += w * kc.y; oacc[10] += w * kc.z; oacc[11] += w * kc.w;
        oacc[12] += w * kd.x; oacc[13] += w * kd.y; oacc[14] += w * kd.z; oacc[15] += w * kd.w;
        optacc[0] += w * kp0;
        optacc[1] += w * kp1;
        optacc[2] += w * kp2;

        // o_pair: pair_z is head-independent -> broadcast w (1 shuffle per target head).
        #pragma unroll
        for (int jh = 0; jh < 8; ++jh) {
            float wj = __shfl(w, (es << 3) + jh);
            opacc[jh][0] += wj * pair4.x;
            opacc[jh][1] += wj * pair4.y;
            opacc[jh][2] += wj * pair4.z;
            opacc[jh][3] += wj * pair4.w;
        }
    }

    // reduce across the 8 edge slots (lane bits 3..5)
    #pragma unroll
    for (int delta = 8; delta <= 32; delta <<= 1) {
        ssum += __shfl_xor(ssum, delta);
        #pragma unroll
        for (int c = 0; c < 16; ++c) oacc[c] += __shfl_xor(oacc[c], delta);
        #pragma unroll
        for (int i = 0; i < 3; ++i) optacc[i] += __shfl_xor(optacc[i], delta);
        #pragma unroll
        for (int j = 0; j < 8; ++j)
            #pragma unroll
            for (int c = 0; c < 4; ++c) opacc[j][c] += __shfl_xor(opacc[j][c], delta);
    }

    // Per-head denominators for o_pair (opacc[jh] used head jh's weights).
    float invj[8];
    #pragma unroll
    for (int jh = 0; jh < 8; ++jh)
        invj[jh] = 1.f / (__shfl(ssum, jh) + 1e-16f);

    if (es == 0) {
        float inv = 1.f / (ssum + 1e-16f);
        float* f = feats + (size_t)s * 416;
        // o -> f[0:128]
        #pragma unroll
        for (int c = 0; c < 16; c += 4) {
            float4 v = make_float4(oacc[c] * inv, oacc[c + 1] * inv, oacc[c + 2] * inv, oacc[c + 3] * inv);
            *(float4*)(&f[h * 16 + c]) = v;
        }
        // o_pt rotate back + norm -> f[128:160]
        const float* T = trans + (size_t)s * 3;
        const float* R = rot + (size_t)s * 9;
        float v0 = optacc[0] * inv - T[0];
        float v1 = optacc[1] * inv - T[1];
        float v2 = optacc[2] * inv - T[2];
        float r0 = R[0] * v0 + R[3] * v1 + R[6] * v2;
        float r1 = R[1] * v0 + R[4] * v1 + R[7] * v2;
        float r2 = R[2] * v0 + R[5] * v1 + R[8] * v2;
        f[128 + h] = r0;
        f[136 + h] = r1;
        f[144 + h] = r2;
        f[152 + h] = sqrtf(r0 * r0 + r1 * r1 + r2 * r2 + 1e-8f);
        // o_pair -> f[160:416]
        #pragma unroll
        for (int jh = 0; jh < 8; ++jh) {
            float4 v = make_float4(opacc[jh][0] * invj[jh], opacc[jh][1] * invj[jh],
                                   opacc[jh][2] * invj[jh], opacc[jh][3] * invj[jh]);
            *(float4*)(&f[160 + jh * 32 + h * 4]) = v;
        }
    }
}

// ---------------- host ----------------
extern "C" void kernel_launch(void* const* d_in, const int* in_sizes, int n_in,
                              void* d_out, int out_size, void* d_ws, size_t ws_size,
                              hipStream_t stream)
{
    const float* frame_s = (const float*)d_in[0];
    const float* tfn     = (const float*)d_in[1];
    const float* z       = (const float*)d_in[2];
    const int*   ei      = (const int*)d_in[3];
    const float* mask    = (const float*)d_in[4];
    const float* rot     = (const float*)d_in[5];
    const float* trans   = (const float*)d_in[6];
    const float* Wq      = (const float*)d_in[7];
    const float* bq      = (const float*)d_in[8];
    const float* Wks     = (const float*)d_in[9];
    const float* Wkv     = (const float*)d_in[10];
    const float* Wqp     = (const float*)d_in[11];
    const float* bqp     = (const float*)d_in[12];
    const float* Wb      = (const float*)d_in[13];
    const float* bb      = (const float*)d_in[14];
    const float* Wdz     = (const float*)d_in[15];
    const float* bdz     = (const float*)d_in[16];
    const float* hw      = (const float*)d_in[17];
    const float* Wout    = (const float*)d_in[18];
    const float* bout    = (const float*)d_in[19];
    float* out = (float*)d_out;

    int n = in_sizes[0] / 384;
    int E = in_sizes[3] / 2;
    const int* dstA = ei;        // edge_index[0]
    const int* srcA = ei + E;    // edge_index[1]

    float* ws = (float*)d_ws;
    size_t p = 0;
    auto alloc = [&](size_t elems) -> float* {
        float* r = ws + p;
        p += (elems + 15) & ~((size_t)15);
        return r;
    };
    float* qqpbuf = alloc((size_t)n * 320);   // [q | qp_raw]
    float* qpts   = alloc((size_t)n * 192);
    float* kbuf   = alloc((size_t)n * 128);
    float* kpts   = alloc((size_t)n * 24);
    float* feats  = alloc((size_t)n * 416);
    float* bpair  = alloc((size_t)E * 40);    // CSR order
    float* wqqpT  = alloc(320 * 384);
    float* bqqp   = alloc(320);
    float* wcatT  = alloc(40 * 128);
    float* bcat   = alloc(64);
    float* wksT   = alloc(128 * 128);
    float* woutT  = alloc(384 * 416);
    int* cnt   = (int*)alloc((size_t)n);
    int* off   = (int*)alloc((size_t)n);
    int* cur   = (int*)alloc((size_t)n);
    int* elist = (int*)alloc((size_t)E);
    int* dsts  = (int*)alloc((size_t)E);

    prep_kernel<<<512, 256, 0, stream>>>(Wq, bq, Wqp, bqp, Wb, bb, Wdz, bdz, Wks, Wout,
                                         wqqpT, bqqp, wcatT, bcat, wksT, woutT, cnt, n);

    count_kernel<<<(E + 255) / 256, 256, 0, stream>>>(srcA, cnt, E);
    scan_kernel<<<1, 1024, 0, stream>>>(cnt, off, cur, n);
    fill_kernel<<<(E + 255) / 256, 256, 0, stream>>>(srcA, dstA, cur, elist, dsts, E);

    {   // [q | qp_raw] = frame_s @ [Wq|Wqp] + [bq|bqp]   (N=320, GBN=160 -> grid.y=2)
        dim3 g((n + 127) / 128, 2);
        gemm_mfma<5, false><<<g, 256, 0, stream>>>(frame_s, 384, nullptr, wqqpT, 384, bqqp, qqpbuf, 320, n, 320, 384);
    }
    {   // k = tfn[:, :128] @ Wk_s
        dim3 g((n + 127) / 128, 1);
        gemm_mfma<4, false><<<g, 256, 0, stream>>>(tfn, 176, nullptr, wksT, 128, nullptr, kbuf, 128, n, 128, 128);
    }
    {   // bpair[pos] = z[elist[pos]] @ [Wb|Wdz] + [bb|bdz]  (CSR order, N=40)
        dim3 g((E + 127) / 128, 1);
        gemm_mfma<2, true><<<g, 256, 0, stream>>>(z, 128, elist, wcatT, 128, bcat, bpair, 40, E, 40, 128);
    }
    kpts_kernel<<<(n * 24 + 255) / 256, 256, 0, stream>>>(tfn, Wkv, kpts, n);
    qpts_kernel<<<(n * 64 + 255) / 256, 256, 0, stream>>>(qqpbuf + 128, rot, trans, qpts, n);

    attn_kernel<<<(n + 3) / 4, 256, 0, stream>>>(off, cnt, dsts,
                                                 qqpbuf, kbuf, qpts, kpts, bpair, mask, hw,
                                                 rot, trans, feats, n);

    {   // out = feats @ Wout + bout   (N=384, GBN=192 -> grid.y=2)
        dim3 g((n + 127) / 128, 2);
        gemm_mfma<6, false><<<g, 256, 0, stream>>>(feats, 416, nullptr, woutT, 416, bout, out, 384, n, 384, 416);
    }
    (void)n_in; (void)out_size; (void)ws_size;
}

// Round 2
// 939.262 us; speedup vs baseline: 1.0292x; 1.0292x over previous
//
#include <hip/hip_runtime.h>
#include <math.h>

typedef __attribute__((ext_vector_type(8))) short short8;
typedef __attribute__((ext_vector_type(4))) float f32x4;

static __device__ inline unsigned short f2bf(float f) {
    union { float f; unsigned u; } v; v.f = f;
    unsigned r = v.u + 0x7FFF + ((v.u >> 16) & 1);
    return (unsigned short)(r >> 16);
}

// ---------------- MFMA bf16 GEMM: C[M,N] = A[M,K] @ BT[N,K]^T + bias ----------------
// Block tile: 128 x (WJ*32), BK=64. 4 waves in 2x2. Wave tile: 64 x (WJ*16).
// SCATTER: output row m is written to C row scat[m] (used to emit bpair in CSR order
// while reading z sequentially -- randomness on the non-blocking write side).
template<int WJ, bool SCATTER>
__global__ __launch_bounds__(256) void gemm_mfma(
    const float* __restrict__ A, int lda,
    const int* __restrict__ scat,
    const float* __restrict__ BT, int ldb,   // BT is [N][K] row-major
    const float* __restrict__ bias,
    float* __restrict__ C, int ldc,
    int M, int N, int K)
{
    constexpr int GBN = WJ * 32;
    __shared__ unsigned short As[128 * 72];
    __shared__ unsigned short Bs[GBN * 72];

    const int t = threadIdx.x;
    const int wid = t >> 6, lane = t & 63;
    const int wm = (wid & 1) * 64;
    const int wn = (wid >> 1) * (WJ * 16);
    const int row16 = lane & 15, quad = lane >> 4;
    const int bm = blockIdx.x * 128;
    const int bn = blockIdx.y * GBN;

    f32x4 acc[4][WJ];
    #pragma unroll
    for (int i = 0; i < 4; ++i)
        #pragma unroll
        for (int j = 0; j < WJ; ++j)
            #pragma unroll
            for (int r = 0; r < 4; ++r) acc[i][j][r] = 0.f;

    const int ktiles = (K + 63) >> 6;
    for (int kt = 0; kt < ktiles; ++kt) {
        const int k0 = kt << 6;
        // stage A: 128 rows x 64 k (sequential rows)
        #pragma unroll
        for (int it = 0; it < 8; ++it) {
            int f = it * 256 + t;
            int row = f >> 4, kq = (f & 15) << 2;
            float4 av = make_float4(0.f, 0.f, 0.f, 0.f);
            if (bm + row < M && k0 + kq < K)
                av = *(const float4*)(A + (size_t)(bm + row) * lda + k0 + kq);
            ushort4 uv;
            uv.x = f2bf(av.x); uv.y = f2bf(av.y); uv.z = f2bf(av.z); uv.w = f2bf(av.w);
            *(ushort4*)(&As[row * 72 + kq]) = uv;
        }
        // stage B: GBN rows x 64 k
        #pragma unroll
        for (int it = 0; it < WJ * 2; ++it) {
            int f = it * 256 + t;
            int row = f >> 4, kq = (f & 15) << 2;
            float4 bv = make_float4(0.f, 0.f, 0.f, 0.f);
            if (bn + row < N && k0 + kq < K)
                bv = *(const float4*)(BT + (size_t)(bn + row) * ldb + k0 + kq);
            ushort4 uv;
            uv.x = f2bf(bv.x); uv.y = f2bf(bv.y); uv.z = f2bf(bv.z); uv.w = f2bf(bv.w);
            *(ushort4*)(&Bs[row * 72 + kq]) = uv;
        }
        __syncthreads();

        #pragma unroll
        for (int ks = 0; ks < 64; ks += 32) {
            short8 af[4], bfv[WJ];
            #pragma unroll
            for (int i = 0; i < 4; ++i)
                af[i] = *(const short8*)(&As[(wm + i * 16 + row16) * 72 + ks + quad * 8]);
            #pragma unroll
            for (int j = 0; j < WJ; ++j)
                bfv[j] = *(const short8*)(&Bs[(wn + j * 16 + row16) * 72 + ks + quad * 8]);
            #pragma unroll
            for (int i = 0; i < 4; ++i)
                #pragma unroll
                for (int j = 0; j < WJ; ++j)
                    acc[i][j] = __builtin_amdgcn_mfma_f32_16x16x32_bf16(af[i], bfv[j], acc[i][j], 0, 0, 0);
        }
        __syncthreads();
    }

    #pragma unroll
    for (int i = 0; i < 4; ++i)
        #pragma unroll
        for (int j = 0; j < WJ; ++j) {
            int col = bn + wn + j * 16 + row16;
            if (col >= N) continue;
            float bv = bias ? bias[col] : 0.f;
            #pragma unroll
            for (int r = 0; r < 4; ++r) {
                int row = bm + wm + i * 16 + quad * 4 + r;
                if (row < M) {
                    size_t orow;
                    if constexpr (SCATTER) orow = (size_t)scat[row];
                    else                   orow = (size_t)row;
                    C[orow * ldc + col] = acc[i][j][r] + bv;
                }
            }
        }
}

// ---------------- prep: transpose/concat weights, fold logit scales, zero cnt ----------------
__global__ void prep_kernel(const float* __restrict__ Wq, const float* __restrict__ bq,
                            const float* __restrict__ Wqp, const float* __restrict__ bqp,
                            const float* __restrict__ Wb, const float* __restrict__ bb,
                            const float* __restrict__ Wdz, const float* __restrict__ bdz,
                            const float* __restrict__ Wks, const float* __restrict__ Wout,
                            float* __restrict__ wqqpT, float* __restrict__ bqqp,
                            float* __restrict__ wcatT, float* __restrict__ bcat,
                            float* __restrict__ wksT, float* __restrict__ woutT,
                            int* __restrict__ cnt, int n)
{
    const float SC_QK = 0.14433756729740643f;   // sqrt(1/48), folded into q
    const float SC_B  = 0.5773502691896258f;    // sqrt(1/3), folded into b
    int gid = blockIdx.x * 256 + threadIdx.x;
    int stride = gridDim.x * 256;
    for (int i = gid; i < n; i += stride) cnt[i] = 0;
    for (int i = gid; i < 320 * 384; i += stride) {
        int o = i / 384, c = i % 384;
        wqqpT[i] = (o < 128) ? Wq[c * 128 + o] * SC_QK : Wqp[c * 192 + (o - 128)];
    }
    for (int i = gid; i < 320; i += stride) bqqp[i] = (i < 128) ? bq[i] * SC_QK : bqp[i - 128];
    for (int i = gid; i < 40 * 128; i += stride) {
        int o = i >> 7, c = i & 127;
        wcatT[i] = (o < 8) ? Wb[c * 8 + o] * SC_B : Wdz[c * 32 + (o - 8)];
    }
    for (int i = gid; i < 40; i += stride) bcat[i] = (i < 8) ? bb[i] * SC_B : bdz[i - 8];
    for (int i = gid; i < 128 * 128; i += stride) {
        int o = i >> 7, c = i & 127;
        wksT[i] = Wks[c * 128 + o];
    }
    for (int i = gid; i < 384 * 416; i += stride) {
        int o = i / 416, c = i % 416;
        woutT[i] = Wout[c * 384 + o];
    }
}

// ---------------- k_pts ----------------
__global__ void kpts_kernel(const float* __restrict__ tfn, const float* __restrict__ Wkv,
                            float* __restrict__ kpts, int n)
{
    int t = blockIdx.x * 256 + threadIdx.x;
    if (t >= n * 24) return;
    int node = t / 24, f = t % 24;
    int a = f >> 3;
    int b = f & 7;
    const float* vr = tfn + (size_t)node * 176 + 128;
    float s = 0.f;
    #pragma unroll
    for (int p = 0; p < 16; ++p) s += vr[p * 3 + a] * Wkv[p * 8 + b];
    kpts[t] = s;
}

// ---------------- q_pts rotation (qpraw has row stride 320, cols 128..319 of qqp) ----------------
__global__ void qpts_kernel(const float* __restrict__ qpraw, const float* __restrict__ rot,
                            const float* __restrict__ trans, float* __restrict__ qpts, int n)
{
    int t = blockIdx.x * 256 + threadIdx.x;
    if (t >= n * 64) return;
    int node = t / 64, hk = t % 64;
    const float* qr = qpraw + (size_t)node * 320;
    float r0 = qr[hk], r1 = qr[64 + hk], r2 = qr[128 + hk];
    const float* R = rot + (size_t)node * 9;
    const float* T = trans + (size_t)node * 3;
    float* o = qpts + (size_t)node * 192 + hk * 3;
    #pragma unroll
    for (int i = 0; i < 3; ++i)
        o[i] = R[i * 3 + 0] * r0 + R[i * 3 + 1] * r1 + R[i * 3 + 2] * r2 + T[i];
}

// ---------------- CSR build ----------------
__global__ void count_kernel(const int* __restrict__ srcA, int* __restrict__ cnt, int E)
{
    int e = blockIdx.x * 256 + threadIdx.x;
    if (e < E) atomicAdd(&cnt[srcA[e]], 1);
}

__global__ void scan_kernel(const int* __restrict__ cnt, int* __restrict__ off,
                            int* __restrict__ cur, int n)
{
    __shared__ int sums[1024];
    int t = threadIdx.x;
    int chunk = (n + 1023) >> 10;
    int begin = t * chunk;
    int local = 0;
    for (int j = 0; j < chunk; ++j) {
        int i = begin + j;
        if (i < n) local += cnt[i];
    }
    sums[t] = local;
    __syncthreads();
    for (int d = 1; d < 1024; d <<= 1) {
        int x = sums[t];
        int y = (t >= d) ? sums[t - d] : 0;
        __syncthreads();
        sums[t] = x + y;
        __syncthreads();
    }
    int run = sums[t] - local;
    for (int j = 0; j < chunk; ++j) {
        int i = begin + j;
        if (i < n) {
            off[i] = run;
            cur[i] = run;
            run += cnt[i];
        }
    }
}

// fill: inv[e] = CSR position (sequential write), dsts[pos] = dst (scattered write).
// elist is gone -- attn never needs edge ids.
__global__ void fill_kernel(const int* __restrict__ srcA, const int* __restrict__ dstA,
                            int* __restrict__ cur, int* __restrict__ inv,
                            int* __restrict__ dsts, int E)
{
    int e = blockIdx.x * 256 + threadIdx.x;
    if (e < E) {
        int s = srcA[e];
        int pos = atomicAdd(&cur[s], 1);
        inv[e] = pos;
        dsts[pos] = dstA[e];
    }
}

// ---------------- attention + aggregation + finalize: one wave per src node ----------------
// lane = es*8 + h : es = edge slot (0..7), h = head (0..7)
// bpair (row stride 48) and dsts are in CSR order -> fully sequential segment reads.
__global__ __launch_bounds__(256) void attn_kernel(
    const int* __restrict__ off, const int* __restrict__ cnt,
    const int* __restrict__ dsts,
    const float* __restrict__ qqp, const float* __restrict__ kbuf,
    const float* __restrict__ qpts, const float* __restrict__ kpts,
    const float* __restrict__ bpair, const float* __restrict__ mask,
    const float* __restrict__ hwin,
    const float* __restrict__ rot, const float* __restrict__ trans,
    float* __restrict__ feats, int n)
{
    int wave = threadIdx.x >> 6;
    int lane = threadIdx.x & 63;
    int s = blockIdx.x * 4 + wave;
    if (s >= n) return;
    int es = lane >> 3;
    int h  = lane & 7;

    float qh[16];
    {
        const float* qp = qqp + (size_t)s * 320 + h * 16;
        #pragma unroll
        for (int c = 0; c < 16; ++c) qh[c] = qp[c];
    }
    float qpt[24];
    {
        const float* pp = qpts + (size_t)s * 192 + h * 24;
        #pragma unroll
        for (int j = 0; j < 24; ++j) qpt[j] = pp[j];
    }
    // softplus(hw) * sqrt(1/108) * 0.5 folded together
    float hwv = log1pf(__expf(hwin[h])) * 0.04811252243246882f;
    float mask_s = mask[s];
    int myoff = off[s], mycnt = cnt[s];

    float ssum = 0.f;
    float oacc[16];
    #pragma unroll
    for (int c = 0; c < 16; ++c) oacc[c] = 0.f;
    float optacc[3] = {0.f, 0.f, 0.f};
    float opacc[8][4];
    #pragma unroll
    for (int j = 0; j < 8; ++j)
        #pragma unroll
        for (int c = 0; c < 4; ++c) opacc[j][c] = 0.f;

    int nb = (mycnt + 7) >> 3;
    for (int b = 0; b < nb; ++b) {
        int idx = b * 8 + es;
        bool valid = idx < mycnt;
        int pos = myoff + (valid ? idx : 0);
        int d = dsts[pos];

        const float* bp = bpair + (size_t)pos * 48;
        float bh = bp[h];
        float4 pair4 = *(const float4*)(bp + 8 + h * 4);

        const float* kr = kbuf + (size_t)d * 128 + h * 16;
        float4 ka = *(const float4*)(kr + 0);
        float4 kb = *(const float4*)(kr + 4);
        float4 kc = *(const float4*)(kr + 8);
        float4 kd = *(const float4*)(kr + 12);

        const float* kp = kpts + (size_t)d * 24 + h * 3;
        float kp0 = kp[0], kp1 = kp[1], kp2 = kp[2];

        float qk = qh[0] * ka.x + qh[1] * ka.y + qh[2] * ka.z + qh[3] * ka.w
                 + qh[4] * kb.x + qh[5] * kb.y + qh[6] * kb.z + qh[7] * kb.w
                 + qh[8] * kc.x + qh[9] * kc.y + qh[10] * kc.z + qh[11] * kc.w
                 + qh[12] * kd.x + qh[13] * kd.y + qh[14] * kd.z + qh[15] * kd.w;

        float pt = 0.f;
        #pragma unroll
        for (int pp = 0; pp < 8; ++pp) {
            float d0 = qpt[pp * 3 + 0] - kp0;
            float d1 = qpt[pp * 3 + 1] - kp1;
            float d2 = qpt[pp * 3 + 2] - kp2;
            pt += d0 * d0 + d1 * d1 + d2 * d2;
        }

        float md = mask[d];
        // qk and bh arrive pre-scaled (folded into weights at prep)
        float logit = qk + bh - hwv * pt + 100000.0f * (mask_s * md - 1.0f);
        float w = valid ? __expf(logit) : 0.f;

        ssum += w;
        oacc[0] += w * ka.x; oacc[1] += w * ka.y; oacc[2] += w * ka.z; oacc[3] += w * ka.w;
        oacc[4] += w * kb.x; oacc[5] += w * kb.y; oacc[6] += w * kb.z; oacc[7] += w * kb.w;
        oacc[8] += w * kc.x; oacc[9] += w * kc.y; oacc[10] += w * kc.z; oacc[11] += w * kc.w;
        oacc[12] += w * kd.x; oacc[13] += w * kd.y; oacc[14] += w * kd.z; oacc[15] += w * kd.w;
        optacc[0] += w * kp0;
        optacc[1] += w * kp1;
        optacc[2] += w * kp2;

        // o_pair: pair_z is head-independent -> broadcast w (1 shuffle per target head).
        #pragma unroll
        for (int jh = 0; jh < 8; ++jh) {
            float wj = __shfl(w, (es << 3) + jh);
            opacc[jh][0] += wj * pair4.x;
            opacc[jh][1] += wj * pair4.y;
            opacc[jh][2] += wj * pair4.z;
            opacc[jh][3] += wj * pair4.w;
        }
    }

    // reduce across the 8 edge slots (lane bits 3..5)
    #pragma unroll
    for (int delta = 8; delta <= 32; delta <<= 1) {
        ssum += __shfl_xor(ssum, delta);
        #pragma unroll
        for (int c = 0; c < 16; ++c) oacc[c] += __shfl_xor(oacc[c], delta);
        #pragma unroll
        for (int i = 0; i < 3; ++i) optacc[i] += __shfl_xor(optacc[i], delta);
        #pragma unroll
        for (int j = 0; j < 8; ++j)
            #pragma unroll
            for (int c = 0; c < 4; ++c) opacc[j][c] += __shfl_xor(opacc[j][c], delta);
    }

    // Per-head denominators for o_pair (opacc[jh] used head jh's weights).
    float invj[8];
    #pragma unroll
    for (int jh = 0; jh < 8; ++jh)
        invj[jh] = 1.f / (__shfl(ssum, jh) + 1e-16f);

    if (es == 0) {
        float inv = 1.f / (ssum + 1e-16f);
        float* f = feats + (size_t)s * 416;
        // o -> f[0:128]
        #pragma unroll
        for (int c = 0; c < 16; c += 4) {
            float4 v = make_float4(oacc[c] * inv, oacc[c + 1] * inv, oacc[c + 2] * inv, oacc[c + 3] * inv);
            *(float4*)(&f[h * 16 + c]) = v;
        }
        // o_pt rotate back + norm -> f[128:160]
        const float* T = trans + (size_t)s * 3;
        const float* R = rot + (size_t)s * 9;
        float v0 = optacc[0] * inv - T[0];
        float v1 = optacc[1] * inv - T[1];
        float v2 = optacc[2] * inv - T[2];
        float r0 = R[0] * v0 + R[3] * v1 + R[6] * v2;
        float r1 = R[1] * v0 + R[4] * v1 + R[7] * v2;
        float r2 = R[2] * v0 + R[5] * v1 + R[8] * v2;
        f[128 + h] = r0;
        f[136 + h] = r1;
        f[144 + h] = r2;
        f[152 + h] = sqrtf(r0 * r0 + r1 * r1 + r2 * r2 + 1e-8f);
        // o_pair -> f[160:416]
        #pragma unroll
        for (int jh = 0; jh < 8; ++jh) {
            float4 v = make_float4(opacc[jh][0] * invj[jh], opacc[jh][1] * invj[jh],
                                   opacc[jh][2] * invj[jh], opacc[jh][3] * invj[jh]);
            *(float4*)(&f[160 + jh * 32 + h * 4]) = v;
        }
    }
}

// ---------------- host ----------------
extern "C" void kernel_launch(void* const* d_in, const int* in_sizes, int n_in,
                              void* d_out, int out_size, void* d_ws, size_t ws_size,
                              hipStream_t stream)
{
    const float* frame_s = (const float*)d_in[0];
    const float* tfn     = (const float*)d_in[1];
    const float* z       = (const float*)d_in[2];
    const int*   ei      = (const int*)d_in[3];
    const float* mask    = (const float*)d_in[4];
    const float* rot     = (const float*)d_in[5];
    const float* trans   = (const float*)d_in[6];
    const float* Wq      = (const float*)d_in[7];
    const float* bq      = (const float*)d_in[8];
    const float* Wks     = (const float*)d_in[9];
    const float* Wkv     = (const float*)d_in[10];
    const float* Wqp     = (const float*)d_in[11];
    const float* bqp     = (const float*)d_in[12];
    const float* Wb      = (const float*)d_in[13];
    const float* bb      = (const float*)d_in[14];
    const float* Wdz     = (const float*)d_in[15];
    const float* bdz     = (const float*)d_in[16];
    const float* hw      = (const float*)d_in[17];
    const float* Wout    = (const float*)d_in[18];
    const float* bout    = (const float*)d_in[19];
    float* out = (float*)d_out;

    int n = in_sizes[0] / 384;
    int E = in_sizes[3] / 2;
    const int* dstA = ei;        // edge_index[0]
    const int* srcA = ei + E;    // edge_index[1]

    float* ws = (float*)d_ws;
    size_t p = 0;
    auto alloc = [&](size_t elems) -> float* {
        float* r = ws + p;
        p += (elems + 15) & ~((size_t)15);
        return r;
    };
    float* qqpbuf = alloc((size_t)n * 320);   // [q | qp_raw]
    float* qpts   = alloc((size_t)n * 192);
    float* kbuf   = alloc((size_t)n * 128);
    float* kpts   = alloc((size_t)n * 24);
    float* feats  = alloc((size_t)n * 416);
    float* bpair  = alloc((size_t)E * 48);    // CSR order, rows padded to 192 B
    float* wqqpT  = alloc(320 * 384);
    float* bqqp   = alloc(320);
    float* wcatT  = alloc(40 * 128);
    float* bcat   = alloc(64);
    float* wksT   = alloc(128 * 128);
    float* woutT  = alloc(384 * 416);
    int* cnt   = (int*)alloc((size_t)n);
    int* off   = (int*)alloc((size_t)n);
    int* cur   = (int*)alloc((size_t)n);
    int* inv   = (int*)alloc((size_t)E);
    int* dsts  = (int*)alloc((size_t)E);

    prep_kernel<<<512, 256, 0, stream>>>(Wq, bq, Wqp, bqp, Wb, bb, Wdz, bdz, Wks, Wout,
                                         wqqpT, bqqp, wcatT, bcat, wksT, woutT, cnt, n);

    count_kernel<<<(E + 255) / 256, 256, 0, stream>>>(srcA, cnt, E);
    scan_kernel<<<1, 1024, 0, stream>>>(cnt, off, cur, n);
    fill_kernel<<<(E + 255) / 256, 256, 0, stream>>>(srcA, dstA, cur, inv, dsts, E);

    {   // [q | qp_raw] = frame_s @ [Wq|Wqp] + [bq|bqp]   (N=320, GBN=160 -> grid.y=2)
        dim3 g((n + 127) / 128, 2);
        gemm_mfma<5, false><<<g, 256, 0, stream>>>(frame_s, 384, nullptr, wqqpT, 384, bqqp, qqpbuf, 320, n, 320, 384);
    }
    {   // k = tfn[:, :128] @ Wk_s
        dim3 g((n + 127) / 128, 1);
        gemm_mfma<4, false><<<g, 256, 0, stream>>>(tfn, 176, nullptr, wksT, 128, nullptr, kbuf, 128, n, 128, 128);
    }
    {   // bpair[inv[e]] = z[e] @ [Wb|Wdz] + [bb|bdz]  (sequential z read, scattered write)
        dim3 g((E + 127) / 128, 1);
        gemm_mfma<2, true><<<g, 256, 0, stream>>>(z, 128, inv, wcatT, 128, bcat, bpair, 48, E, 40, 128);
    }
    kpts_kernel<<<(n * 24 + 255) / 256, 256, 0, stream>>>(tfn, Wkv, kpts, n);
    qpts_kernel<<<(n * 64 + 255) / 256, 256, 0, stream>>>(qqpbuf + 128, rot, trans, qpts, n);

    attn_kernel<<<(n + 3) / 4, 256, 0, stream>>>(off, cnt, dsts,
                                                 qqpbuf, kbuf, qpts, kpts, bpair, mask, hw,
                                                 rot, trans, feats, n);

    {   // out = feats @ Wout + bout   (N=384, GBN=192 -> grid.y=2)
        dim3 g((n + 127) / 128, 2);
        gemm_mfma<6, false><<<g, 256, 0, stream>>>(feats, 416, nullptr, woutT, 416, bout, out, 384, n, 384, 416);
    }
    (void)n_in; (void)out_size; (void)ws_size;
}

// Round 3
// 914.210 us; speedup vs baseline: 1.0574x; 1.0274x over previous
//
#include <hip/hip_runtime.h>
#include <math.h>

typedef __attribute__((ext_vector_type(8))) short short8;
typedef __attribute__((ext_vector_type(4))) float f32x4;

static __device__ inline unsigned short f2bf(float f) {
    union { float f; unsigned u; } v; v.f = f;
    unsigned r = v.u + 0x7FFF + ((v.u >> 16) & 1);
    return (unsigned short)(r >> 16);
}

// ---------------- MFMA bf16 GEMM body: C[M,N] = A[M,K] @ BT[N,K]^T + bias ----------------
// Block tile: 128 x (WJ*32), BK=64. 4 waves in 2x2. Wave tile: 64 x (WJ*16).
template<int WJ>
__device__ __forceinline__ void gemm_body(
    unsigned short* __restrict__ As, unsigned short* __restrict__ Bs,
    const float* __restrict__ A, int lda,
    const float* __restrict__ BT, int ldb,   // BT is [N][K] row-major
    const float* __restrict__ bias,
    float* __restrict__ C, int ldc,
    int M, int N, int K, int bx, int by)
{
    constexpr int GBN = WJ * 32;
    const int t = threadIdx.x;
    const int wid = t >> 6, lane = t & 63;
    const int wm = (wid & 1) * 64;
    const int wn = (wid >> 1) * (WJ * 16);
    const int row16 = lane & 15, quad = lane >> 4;
    const int bm = bx * 128;
    const int bn = by * GBN;

    f32x4 acc[4][WJ];
    #pragma unroll
    for (int i = 0; i < 4; ++i)
        #pragma unroll
        for (int j = 0; j < WJ; ++j)
            #pragma unroll
            for (int r = 0; r < 4; ++r) acc[i][j][r] = 0.f;

    const int ktiles = (K + 63) >> 6;
    for (int kt = 0; kt < ktiles; ++kt) {
        const int k0 = kt << 6;
        // stage A: 128 rows x 64 k
        #pragma unroll
        for (int it = 0; it < 8; ++it) {
            int f = it * 256 + t;
            int row = f >> 4, kq = (f & 15) << 2;
            float4 av = make_float4(0.f, 0.f, 0.f, 0.f);
            if (bm + row < M && k0 + kq < K)
                av = *(const float4*)(A + (size_t)(bm + row) * lda + k0 + kq);
            ushort4 uv;
            uv.x = f2bf(av.x); uv.y = f2bf(av.y); uv.z = f2bf(av.z); uv.w = f2bf(av.w);
            *(ushort4*)(&As[row * 72 + kq]) = uv;
        }
        // stage B: GBN rows x 64 k
        #pragma unroll
        for (int it = 0; it < WJ * 2; ++it) {
            int f = it * 256 + t;
            int row = f >> 4, kq = (f & 15) << 2;
            float4 bv = make_float4(0.f, 0.f, 0.f, 0.f);
            if (bn + row < N && k0 + kq < K)
                bv = *(const float4*)(BT + (size_t)(bn + row) * ldb + k0 + kq);
            ushort4 uv;
            uv.x = f2bf(bv.x); uv.y = f2bf(bv.y); uv.z = f2bf(bv.z); uv.w = f2bf(bv.w);
            *(ushort4*)(&Bs[row * 72 + kq]) = uv;
        }
        __syncthreads();

        #pragma unroll
        for (int ks = 0; ks < 64; ks += 32) {
            short8 af[4], bfv[WJ];
            #pragma unroll
            for (int i = 0; i < 4; ++i)
                af[i] = *(const short8*)(&As[(wm + i * 16 + row16) * 72 + ks + quad * 8]);
            #pragma unroll
            for (int j = 0; j < WJ; ++j)
                bfv[j] = *(const short8*)(&Bs[(wn + j * 16 + row16) * 72 + ks + quad * 8]);
            #pragma unroll
            for (int i = 0; i < 4; ++i)
                #pragma unroll
                for (int j = 0; j < WJ; ++j)
                    acc[i][j] = __builtin_amdgcn_mfma_f32_16x16x32_bf16(af[i], bfv[j], acc[i][j], 0, 0, 0);
        }
        __syncthreads();
    }

    #pragma unroll
    for (int i = 0; i < 4; ++i)
        #pragma unroll
        for (int j = 0; j < WJ; ++j) {
            int col = bn + wn + j * 16 + row16;
            if (col >= N) continue;
            float bv = bias ? bias[col] : 0.f;
            #pragma unroll
            for (int r = 0; r < 4; ++r) {
                int row = bm + wm + i * 16 + quad * 4 + r;
                if (row < M) C[(size_t)row * ldc + col] = acc[i][j][r] + bv;
            }
        }
}

template<int WJ>
__global__ __launch_bounds__(256) void gemm_mfma(
    const float* __restrict__ A, int lda,
    const float* __restrict__ BT, int ldb,
    const float* __restrict__ bias,
    float* __restrict__ C, int ldc,
    int M, int N, int K)
{
    __shared__ unsigned short As[128 * 72];
    __shared__ unsigned short Bs[WJ * 32 * 72];
    gemm_body<WJ>(As, Bs, A, lda, BT, ldb, bias, C, ldc, M, N, K, blockIdx.x, blockIdx.y);
}

// ---------------- mega kernel: bpair GEMM + qqp GEMM + k GEMM + kpts + fill ----------------
// All five are mutually independent; packed into one launch via blockIdx ranges.
__global__ __launch_bounds__(256) void mega_kernel(
    // bpair gemm (sequential read & write, edge order)
    const float* __restrict__ z, const float* __restrict__ wcatT,
    const float* __restrict__ bcat, float* __restrict__ bpair, int E,
    // qqp gemm
    const float* __restrict__ frame_s, const float* __restrict__ wqqpT,
    const float* __restrict__ bqqp, float* __restrict__ qqp, int n,
    // k gemm
    const float* __restrict__ tfn, const float* __restrict__ wksT,
    float* __restrict__ kbuf,
    // kpts
    const float* __restrict__ Wkv, float* __restrict__ kpts,
    // fill (CSR elist build)
    const int* __restrict__ srcA, int* __restrict__ cur, int* __restrict__ elist,
    // block partition
    int nb_bp, int nb_qqp_x, int nb_qqp, int nb_k, int nb_kpts)
{
    __shared__ unsigned short As[128 * 72];
    __shared__ unsigned short Bs[128 * 72];   // max over branches (WJ=4)
    int b = blockIdx.x;
    if (b < nb_bp) {          // bpair = z @ [Wb|Wdz] + [bb|bdz]  (N=40, WJ=2)
        gemm_body<2>(As, Bs, z, 128, wcatT, 128, bcat, bpair, 40, E, 40, 128, b, 0);
        return;
    }
    b -= nb_bp;
    if (b < nb_qqp) {         // [q | qp_raw] = frame_s @ [Wq|Wqp] + bias  (N=320, WJ=4)
        gemm_body<4>(As, Bs, frame_s, 384, wqqpT, 384, bqqp, qqp, 320, n, 320, 384,
                     b % nb_qqp_x, b / nb_qqp_x);
        return;
    }
    b -= nb_qqp;
    if (b < nb_k) {           // k = tfn[:, :128] @ Wk_s  (N=128, WJ=4)
        gemm_body<4>(As, Bs, tfn, 176, wksT, 128, nullptr, kbuf, 128, n, 128, 128, b, 0);
        return;
    }
    b -= nb_k;
    if (b < nb_kpts) {        // k_pts
        int t = b * 256 + threadIdx.x;
        if (t < n * 24) {
            int node = t / 24, f = t % 24;
            int a = f >> 3;
            int bb2 = f & 7;
            const float* vr = tfn + (size_t)node * 176 + 128;
            float s = 0.f;
            #pragma unroll
            for (int p = 0; p < 16; ++p) s += vr[p * 3 + a] * Wkv[p * 8 + bb2];
            kpts[t] = s;
        }
        return;
    }
    b -= nb_kpts;
    {                         // fill: CSR edge list
        int e = b * 256 + threadIdx.x;
        if (e < E) {
            int s = srcA[e];
            int pos = atomicAdd(&cur[s], 1);
            elist[pos] = e;
        }
    }
}

// ---------------- prep: transpose/concat weights, fold logit scales, zero cnt ----------------
__global__ void prep_kernel(const float* __restrict__ Wq, const float* __restrict__ bq,
                            const float* __restrict__ Wqp, const float* __restrict__ bqp,
                            const float* __restrict__ Wb, const float* __restrict__ bb,
                            const float* __restrict__ Wdz, const float* __restrict__ bdz,
                            const float* __restrict__ Wks, const float* __restrict__ Wout,
                            float* __restrict__ wqqpT, float* __restrict__ bqqp,
                            float* __restrict__ wcatT, float* __restrict__ bcat,
                            float* __restrict__ wksT, float* __restrict__ woutT,
                            int* __restrict__ cnt, int n)
{
    const float SC_QK = 0.14433756729740643f;   // sqrt(1/48), folded into q
    const float SC_B  = 0.5773502691896258f;    // sqrt(1/3), folded into b
    int gid = blockIdx.x * 256 + threadIdx.x;
    int stride = gridDim.x * 256;
    for (int i = gid; i < n; i += stride) cnt[i] = 0;
    for (int i = gid; i < 320 * 384; i += stride) {
        int o = i / 384, c = i % 384;
        wqqpT[i] = (o < 128) ? Wq[c * 128 + o] * SC_QK : Wqp[c * 192 + (o - 128)];
    }
    for (int i = gid; i < 320; i += stride) bqqp[i] = (i < 128) ? bq[i] * SC_QK : bqp[i - 128];
    for (int i = gid; i < 40 * 128; i += stride) {
        int o = i >> 7, c = i & 127;
        wcatT[i] = (o < 8) ? Wb[c * 8 + o] * SC_B : Wdz[c * 32 + (o - 8)];
    }
    for (int i = gid; i < 40; i += stride) bcat[i] = (i < 8) ? bb[i] * SC_B : bdz[i - 8];
    for (int i = gid; i < 128 * 128; i += stride) {
        int o = i >> 7, c = i & 127;
        wksT[i] = Wks[c * 128 + o];
    }
    for (int i = gid; i < 384 * 416; i += stride) {
        int o = i / 416, c = i % 416;
        woutT[i] = Wout[c * 384 + o];
    }
}

// ---------------- CSR build ----------------
__global__ void count_kernel(const int* __restrict__ srcA, int* __restrict__ cnt, int E)
{
    int e = blockIdx.x * 256 + threadIdx.x;
    if (e < E) atomicAdd(&cnt[srcA[e]], 1);
}

__global__ void scan_kernel(const int* __restrict__ cnt, int* __restrict__ off,
                            int* __restrict__ cur, int n)
{
    __shared__ int sums[1024];
    int t = threadIdx.x;
    int chunk = (n + 1023) >> 10;
    int begin = t * chunk;
    int local = 0;
    for (int j = 0; j < chunk; ++j) {
        int i = begin + j;
        if (i < n) local += cnt[i];
    }
    sums[t] = local;
    __syncthreads();
    for (int d = 1; d < 1024; d <<= 1) {
        int x = sums[t];
        int y = (t >= d) ? sums[t - d] : 0;
        __syncthreads();
        sums[t] = x + y;
        __syncthreads();
    }
    int run = sums[t] - local;
    for (int j = 0; j < chunk; ++j) {
        int i = begin + j;
        if (i < n) {
            off[i] = run;
            cur[i] = run;
            run += cnt[i];
        }
    }
}

// ---------------- attention + aggregation + finalize (qpts computed inline) ----------------
// lane = es*8 + h : es = edge slot (0..7), h = head (0..7)
__global__ __launch_bounds__(256) void attn_kernel(
    const int* __restrict__ off, const int* __restrict__ cnt,
    const int* __restrict__ elist, const int* __restrict__ dstA,
    const float* __restrict__ qqp, const float* __restrict__ kbuf,
    const float* __restrict__ kpts,
    const float* __restrict__ bpair, const float* __restrict__ mask,
    const float* __restrict__ hwin,
    const float* __restrict__ rot, const float* __restrict__ trans,
    float* __restrict__ feats, int n)
{
    int wave = threadIdx.x >> 6;
    int lane = threadIdx.x & 63;
    int s = blockIdx.x * 4 + wave;
    if (s >= n) return;
    int es = lane >> 3;
    int h  = lane & 7;

    float qh[16];
    {
        const float* qp = qqp + (size_t)s * 320 + h * 16;
        #pragma unroll
        for (int c = 0; c < 16; ++c) qh[c] = qp[c];
    }
    // rotation + translation (also reused in epilogue)
    const float* Rp = rot + (size_t)s * 9;
    const float* Tp = trans + (size_t)s * 3;
    float R0 = Rp[0], R1 = Rp[1], R2 = Rp[2];
    float R3 = Rp[3], R4 = Rp[4], R5 = Rp[5];
    float R6 = Rp[6], R7 = Rp[7], R8 = Rp[8];
    float T0 = Tp[0], T1 = Tp[1], T2 = Tp[2];
    // q_pts for head h, computed inline (was a separate kernel + 30 MB round-trip)
    float qpt[24];
    {
        const float* qr = qqp + (size_t)s * 320 + 128 + h * 8;
        #pragma unroll
        for (int p2 = 0; p2 < 8; ++p2) {
            float c0 = qr[p2], c1 = qr[64 + p2], c2 = qr[128 + p2];
            qpt[p2 * 3 + 0] = R0 * c0 + R1 * c1 + R2 * c2 + T0;
            qpt[p2 * 3 + 1] = R3 * c0 + R4 * c1 + R5 * c2 + T1;
            qpt[p2 * 3 + 2] = R6 * c0 + R7 * c1 + R8 * c2 + T2;
        }
    }
    // softplus(hw) * sqrt(1/108) * 0.5 folded together
    float hwv = log1pf(__expf(hwin[h])) * 0.04811252243246882f;
    float mask_s = mask[s];
    int myoff = off[s], mycnt = cnt[s];

    float ssum = 0.f;
    float oacc[16];
    #pragma unroll
    for (int c = 0; c < 16; ++c) oacc[c] = 0.f;
    float optacc[3] = {0.f, 0.f, 0.f};
    float opacc[8][4];
    #pragma unroll
    for (int j = 0; j < 8; ++j)
        #pragma unroll
        for (int c = 0; c < 4; ++c) opacc[j][c] = 0.f;

    int nb = (mycnt + 7) >> 3;
    for (int b = 0; b < nb; ++b) {
        int idx = b * 8 + es;
        bool valid = idx < mycnt;
        int e = valid ? elist[myoff + idx] : 0;
        int d = dstA[e];

        const float* kr = kbuf + (size_t)d * 128 + h * 16;
        float4 ka = *(const float4*)(kr + 0);
        float4 kb = *(const float4*)(kr + 4);
        float4 kc = *(const float4*)(kr + 8);
        float4 kd = *(const float4*)(kr + 12);

        const float* kp = kpts + (size_t)d * 24 + h * 3;
        float kp0 = kp[0], kp1 = kp[1], kp2 = kp[2];

        const float* bp = bpair + (size_t)e * 40;
        float bh = bp[h];
        float4 pair4 = *(const float4*)(bp + 8 + h * 4);

        float qk = qh[0] * ka.x + qh[1] * ka.y + qh[2] * ka.z + qh[3] * ka.w
                 + qh[4] * kb.x + qh[5] * kb.y + qh[6] * kb.z + qh[7] * kb.w
                 + qh[8] * kc.x + qh[9] * kc.y + qh[10] * kc.z + qh[11] * kc.w
                 + qh[12] * kd.x + qh[13] * kd.y + qh[14] * kd.z + qh[15] * kd.w;

        float pt = 0.f;
        #pragma unroll
        for (int pp = 0; pp < 8; ++pp) {
            float d0 = qpt[pp * 3 + 0] - kp0;
            float d1 = qpt[pp * 3 + 1] - kp1;
            float d2 = qpt[pp * 3 + 2] - kp2;
            pt += d0 * d0 + d1 * d1 + d2 * d2;
        }

        float md = mask[d];
        // qk and bh arrive pre-scaled (folded into weights at prep)
        float logit = qk + bh - hwv * pt + 100000.0f * (mask_s * md - 1.0f);
        float w = valid ? __expf(logit) : 0.f;

        ssum += w;
        oacc[0] += w * ka.x; oacc[1] += w * ka.y; oacc[2] += w * ka.z; oacc[3] += w * ka.w;
        oacc[4] += w * kb.x; oacc[5] += w * kb.y; oacc[6] += w * kb.z; oacc[7] += w * kb.w;
        oacc[8] += w * kc.x; oacc[9] += w * kc.y; oacc[10] += w * kc.z; oacc[11] += w * kc.w;
        oacc[12] += w * kd.x; oacc[13] += w * kd.y; oacc[14] += w * kd.z; oacc[15] += w * kd.w;
        optacc[0] += w * kp0;
        optacc[1] += w * kp1;
        optacc[2] += w * kp2;

        // o_pair: pair_z is head-independent -> broadcast w (1 shuffle per target head).
        #pragma unroll
        for (int jh = 0; jh < 8; ++jh) {
            float wj = __shfl(w, (es << 3) + jh);
            opacc[jh][0] += wj * pair4.x;
            opacc[jh][1] += wj * pair4.y;
            opacc[jh][2] += wj * pair4.z;
            opacc[jh][3] += wj * pair4.w;
        }
    }

    // reduce across the 8 edge slots (lane bits 3..5)
    #pragma unroll
    for (int delta = 8; delta <= 32; delta <<= 1) {
        ssum += __shfl_xor(ssum, delta);
        #pragma unroll
        for (int c = 0; c < 16; ++c) oacc[c] += __shfl_xor(oacc[c], delta);
        #pragma unroll
        for (int i = 0; i < 3; ++i) optacc[i] += __shfl_xor(optacc[i], delta);
        #pragma unroll
        for (int j = 0; j < 8; ++j)
            #pragma unroll
            for (int c = 0; c < 4; ++c) opacc[j][c] += __shfl_xor(opacc[j][c], delta);
    }

    // Per-head denominators for o_pair (opacc[jh] used head jh's weights).
    float invj[8];
    #pragma unroll
    for (int jh = 0; jh < 8; ++jh)
        invj[jh] = 1.f / (__shfl(ssum, jh) + 1e-16f);

    if (es == 0) {
        float inv = 1.f / (ssum + 1e-16f);
        float* f = feats + (size_t)s * 416;
        // o -> f[0:128]
        #pragma unroll
        for (int c = 0; c < 16; c += 4) {
            float4 v = make_float4(oacc[c] * inv, oacc[c + 1] * inv, oacc[c + 2] * inv, oacc[c + 3] * inv);
            *(float4*)(&f[h * 16 + c]) = v;
        }
        // o_pt rotate back + norm -> f[128:160] (R,T already in registers)
        float v0 = optacc[0] * inv - T0;
        float v1 = optacc[1] * inv - T1;
        float v2 = optacc[2] * inv - T2;
        float r0 = R0 * v0 + R3 * v1 + R6 * v2;
        float r1 = R1 * v0 + R4 * v1 + R7 * v2;
        float r2 = R2 * v0 + R5 * v1 + R8 * v2;
        f[128 + h] = r0;
        f[136 + h] = r1;
        f[144 + h] = r2;
        f[152 + h] = sqrtf(r0 * r0 + r1 * r1 + r2 * r2 + 1e-8f);
        // o_pair -> f[160:416]
        #pragma unroll
        for (int jh = 0; jh < 8; ++jh) {
            float4 v = make_float4(opacc[jh][0] * invj[jh], opacc[jh][1] * invj[jh],
                                   opacc[jh][2] * invj[jh], opacc[jh][3] * invj[jh]);
            *(float4*)(&f[160 + jh * 32 + h * 4]) = v;
        }
    }
}

// ---------------- host ----------------
extern "C" void kernel_launch(void* const* d_in, const int* in_sizes, int n_in,
                              void* d_out, int out_size, void* d_ws, size_t ws_size,
                              hipStream_t stream)
{
    const float* frame_s = (const float*)d_in[0];
    const float* tfn     = (const float*)d_in[1];
    const float* z       = (const float*)d_in[2];
    const int*   ei      = (const int*)d_in[3];
    const float* mask    = (const float*)d_in[4];
    const float* rot     = (const float*)d_in[5];
    const float* trans   = (const float*)d_in[6];
    const float* Wq      = (const float*)d_in[7];
    const float* bq      = (const float*)d_in[8];
    const float* Wks     = (const float*)d_in[9];
    const float* Wkv     = (const float*)d_in[10];
    const float* Wqp     = (const float*)d_in[11];
    const float* bqp     = (const float*)d_in[12];
    const float* Wb      = (const float*)d_in[13];
    const float* bb      = (const float*)d_in[14];
    const float* Wdz     = (const float*)d_in[15];
    const float* bdz     = (const float*)d_in[16];
    const float* hw      = (const float*)d_in[17];
    const float* Wout    = (const float*)d_in[18];
    const float* bout    = (const float*)d_in[19];
    float* out = (float*)d_out;

    int n = in_sizes[0] / 384;
    int E = in_sizes[3] / 2;
    const int* dstA = ei;        // edge_index[0]
    const int* srcA = ei + E;    // edge_index[1]

    float* ws = (float*)d_ws;
    size_t p = 0;
    auto alloc = [&](size_t elems) -> float* {
        float* r = ws + p;
        p += (elems + 15) & ~((size_t)15);
        return r;
    };
    float* qqpbuf = alloc((size_t)n * 320);   // [q | qp_raw]
    float* kbuf   = alloc((size_t)n * 128);
    float* kpts   = alloc((size_t)n * 24);
    float* feats  = alloc((size_t)n * 416);
    float* bpair  = alloc((size_t)E * 40);    // edge order, sequential write
    float* wqqpT  = alloc(320 * 384);
    float* bqqp   = alloc(320);
    float* wcatT  = alloc(40 * 128);
    float* bcat   = alloc(64);
    float* wksT   = alloc(128 * 128);
    float* woutT  = alloc(384 * 416);
    int* cnt   = (int*)alloc((size_t)n);
    int* off   = (int*)alloc((size_t)n);
    int* cur   = (int*)alloc((size_t)n);
    int* elist = (int*)alloc((size_t)E);

    prep_kernel<<<512, 256, 0, stream>>>(Wq, bq, Wqp, bqp, Wb, bb, Wdz, bdz, Wks, Wout,
                                         wqqpT, bqqp, wcatT, bcat, wksT, woutT, cnt, n);

    count_kernel<<<(E + 255) / 256, 256, 0, stream>>>(srcA, cnt, E);
    scan_kernel<<<1, 1024, 0, stream>>>(cnt, off, cur, n);

    // mega: bpair GEMM + qqp GEMM + k GEMM + kpts + fill, one launch
    int nb_bp    = (E + 127) / 128;
    int nb_qqp_x = (n + 127) / 128;
    int nb_qqp   = nb_qqp_x * 3;              // N=320 -> 3 tiles of 128
    int nb_k     = (n + 127) / 128;
    int nb_kpts  = (n * 24 + 255) / 256;
    int nb_fill  = (E + 255) / 256;
    int nb_total = nb_bp + nb_qqp + nb_k + nb_kpts + nb_fill;
    mega_kernel<<<nb_total, 256, 0, stream>>>(
        z, wcatT, bcat, bpair, E,
        frame_s, wqqpT, bqqp, qqpbuf, n,
        tfn, wksT, kbuf,
        Wkv, kpts,
        srcA, cur, elist,
        nb_bp, nb_qqp_x, nb_qqp, nb_k, nb_kpts);

    attn_kernel<<<(n + 3) / 4, 256, 0, stream>>>(off, cnt, elist, dstA,
                                                 qqpbuf, kbuf, kpts, bpair, mask, hw,
                                                 rot, trans, feats, n);

    {   // out = feats @ Wout + bout
        dim3 g((n + 127) / 128, 3);
        gemm_mfma<4><<<g, 256, 0, stream>>>(feats, 416, woutT, 416, bout, out, 384, n, 384, 416);
    }
    (void)n_in; (void)out_size; (void)ws_size;
}

// Round 4
// 856.949 us; speedup vs baseline: 1.1281x; 1.0668x over previous
//
#include <hip/hip_runtime.h>
#include <math.h>

typedef __attribute__((ext_vector_type(8))) short short8;
typedef __attribute__((ext_vector_type(4))) float f32x4;

static __device__ inline unsigned short f2bf(float f) {
    union { float f; unsigned u; } v; v.f = f;
    unsigned r = v.u + 0x7FFF + ((v.u >> 16) & 1);
    return (unsigned short)(r >> 16);
}

// ---------------- MFMA bf16 GEMM body: C[M,N] = A[M,K] @ BT[N,K]^T + bias ----------------
// Block tile: 128 x (WJ*32), BK=64. 4 waves in 2x2. Wave tile: 64 x (WJ*16).
template<int WJ>
__device__ __forceinline__ void gemm_body(
    unsigned short* __restrict__ As, unsigned short* __restrict__ Bs,
    const float* __restrict__ A, int lda,
    const float* __restrict__ BT, int ldb,   // BT is [N][K] row-major
    const float* __restrict__ bias,
    float* __restrict__ C, int ldc,
    int M, int N, int K, int bx, int by)
{
    constexpr int GBN = WJ * 32;
    const int t = threadIdx.x;
    const int wid = t >> 6, lane = t & 63;
    const int wm = (wid & 1) * 64;
    const int wn = (wid >> 1) * (WJ * 16);
    const int row16 = lane & 15, quad = lane >> 4;
    const int bm = bx * 128;
    const int bn = by * GBN;

    f32x4 acc[4][WJ];
    #pragma unroll
    for (int i = 0; i < 4; ++i)
        #pragma unroll
        for (int j = 0; j < WJ; ++j)
            #pragma unroll
            for (int r = 0; r < 4; ++r) acc[i][j][r] = 0.f;

    const int ktiles = (K + 63) >> 6;
    for (int kt = 0; kt < ktiles; ++kt) {
        const int k0 = kt << 6;
        // stage A: 128 rows x 64 k
        #pragma unroll
        for (int it = 0; it < 8; ++it) {
            int f = it * 256 + t;
            int row = f >> 4, kq = (f & 15) << 2;
            float4 av = make_float4(0.f, 0.f, 0.f, 0.f);
            if (bm + row < M && k0 + kq < K)
                av = *(const float4*)(A + (size_t)(bm + row) * lda + k0 + kq);
            ushort4 uv;
            uv.x = f2bf(av.x); uv.y = f2bf(av.y); uv.z = f2bf(av.z); uv.w = f2bf(av.w);
            *(ushort4*)(&As[row * 72 + kq]) = uv;
        }
        // stage B: GBN rows x 64 k
        #pragma unroll
        for (int it = 0; it < WJ * 2; ++it) {
            int f = it * 256 + t;
            int row = f >> 4, kq = (f & 15) << 2;
            float4 bv = make_float4(0.f, 0.f, 0.f, 0.f);
            if (bn + row < N && k0 + kq < K)
                bv = *(const float4*)(BT + (size_t)(bn + row) * ldb + k0 + kq);
            ushort4 uv;
            uv.x = f2bf(bv.x); uv.y = f2bf(bv.y); uv.z = f2bf(bv.z); uv.w = f2bf(bv.w);
            *(ushort4*)(&Bs[row * 72 + kq]) = uv;
        }
        __syncthreads();

        #pragma unroll
        for (int ks = 0; ks < 64; ks += 32) {
            short8 af[4], bfv[WJ];
            #pragma unroll
            for (int i = 0; i < 4; ++i)
                af[i] = *(const short8*)(&As[(wm + i * 16 + row16) * 72 + ks + quad * 8]);
            #pragma unroll
            for (int j = 0; j < WJ; ++j)
                bfv[j] = *(const short8*)(&Bs[(wn + j * 16 + row16) * 72 + ks + quad * 8]);
            #pragma unroll
            for (int i = 0; i < 4; ++i)
                #pragma unroll
                for (int j = 0; j < WJ; ++j)
                    acc[i][j] = __builtin_amdgcn_mfma_f32_16x16x32_bf16(af[i], bfv[j], acc[i][j], 0, 0, 0);
        }
        __syncthreads();
    }

    #pragma unroll
    for (int i = 0; i < 4; ++i)
        #pragma unroll
        for (int j = 0; j < WJ; ++j) {
            int col = bn + wn + j * 16 + row16;
            if (col >= N) continue;
            float bv = bias ? bias[col] : 0.f;
            #pragma unroll
            for (int r = 0; r < 4; ++r) {
                int row = bm + wm + i * 16 + quad * 4 + r;
                if (row < M) C[(size_t)row * ldc + col] = acc[i][j][r] + bv;
            }
        }
}

template<int WJ>
__global__ __launch_bounds__(256) void gemm_mfma(
    const float* __restrict__ A, int lda,
    const float* __restrict__ BT, int ldb,
    const float* __restrict__ bias,
    float* __restrict__ C, int ldc,
    int M, int N, int K)
{
    __shared__ unsigned short As[128 * 72];
    __shared__ unsigned short Bs[WJ * 32 * 72];
    gemm_body<WJ>(As, Bs, A, lda, BT, ldb, bias, C, ldc, M, N, K, blockIdx.x, blockIdx.y);
}

// ---------------- bpair streaming GEMM: N=40, K=128, B held in registers ----------------
// Zero LDS, zero __syncthreads. Each wave streams 32-row strips of z:
// 16 independent float4 loads -> cvt -> 24 MFMA -> store. Pure HBM stream.
__global__ __launch_bounds__(256) void bpair_stream(
    const float* __restrict__ z, const float* __restrict__ wcatT,
    const float* __restrict__ bcat, float* __restrict__ bpair, int E)
{
    const int lane = threadIdx.x & 63;
    const int wid = threadIdx.x >> 6;
    const int row16 = lane & 15, quad = lane >> 4;

    // Preload B fragments (whole 40x128 weight) + bias into registers.
    // bfv[j][ks]: col = j*16+row16, k = ks*32 + quad*8 + e  (zero-pad cols 40..47)
    short8 bfv[3][4];
    float bj[3];
    #pragma unroll
    for (int j = 0; j < 3; ++j) {
        int col = j * 16 + row16;
        bool cv = col < 40;
        bj[j] = cv ? bcat[col] : 0.f;
        #pragma unroll
        for (int ks = 0; ks < 4; ++ks) {
            float4 w0 = make_float4(0.f, 0.f, 0.f, 0.f);
            float4 w1 = make_float4(0.f, 0.f, 0.f, 0.f);
            if (cv) {
                const float* wp = wcatT + (size_t)col * 128 + ks * 32 + quad * 8;
                w0 = *(const float4*)(wp);
                w1 = *(const float4*)(wp + 4);
            }
            short8 f;
            f[0] = (short)f2bf(w0.x); f[1] = (short)f2bf(w0.y);
            f[2] = (short)f2bf(w0.z); f[3] = (short)f2bf(w0.w);
            f[4] = (short)f2bf(w1.x); f[5] = (short)f2bf(w1.y);
            f[6] = (short)f2bf(w1.z); f[7] = (short)f2bf(w1.w);
            bfv[j][ks] = f;
        }
    }

    const int nstrips = (E + 31) >> 5;
    const int gw = blockIdx.x * 4 + wid;
    const int nw = gridDim.x * 4;
    for (int st = gw; st < nstrips; st += nw) {
        const int r0 = st * 32;
        // Load A fragments: af[i][ks], row = r0 + i*16 + row16, k = ks*32 + quad*8 + e
        short8 af[2][4];
        #pragma unroll
        for (int i = 0; i < 2; ++i) {
            int row = r0 + i * 16 + row16;
            bool rv = row < E;
            const float* zp = z + (size_t)row * 128 + quad * 8;
            #pragma unroll
            for (int ks = 0; ks < 4; ++ks) {
                float4 a0 = make_float4(0.f, 0.f, 0.f, 0.f);
                float4 a1 = make_float4(0.f, 0.f, 0.f, 0.f);
                if (rv) {
                    a0 = *(const float4*)(zp + ks * 32);
                    a1 = *(const float4*)(zp + ks * 32 + 4);
                }
                short8 f;
                f[0] = (short)f2bf(a0.x); f[1] = (short)f2bf(a0.y);
                f[2] = (short)f2bf(a0.z); f[3] = (short)f2bf(a0.w);
                f[4] = (short)f2bf(a1.x); f[5] = (short)f2bf(a1.y);
                f[6] = (short)f2bf(a1.z); f[7] = (short)f2bf(a1.w);
                af[i][ks] = f;
            }
        }

        f32x4 acc[2][3];
        #pragma unroll
        for (int i = 0; i < 2; ++i)
            #pragma unroll
            for (int j = 0; j < 3; ++j)
                #pragma unroll
                for (int r = 0; r < 4; ++r) acc[i][j][r] = 0.f;

        #pragma unroll
        for (int ks = 0; ks < 4; ++ks)
            #pragma unroll
            for (int i = 0; i < 2; ++i)
                #pragma unroll
                for (int j = 0; j < 3; ++j)
                    acc[i][j] = __builtin_amdgcn_mfma_f32_16x16x32_bf16(af[i][ks], bfv[j][ks], acc[i][j], 0, 0, 0);

        #pragma unroll
        for (int i = 0; i < 2; ++i)
            #pragma unroll
            for (int j = 0; j < 3; ++j) {
                int col = j * 16 + row16;
                if (col >= 40) continue;
                #pragma unroll
                for (int r = 0; r < 4; ++r) {
                    int row = r0 + i * 16 + quad * 4 + r;
                    if (row < E) bpair[(size_t)row * 40 + col] = acc[i][j][r] + bj[j];
                }
            }
    }
}

// ---------------- mega2: qqp GEMM + k GEMM + kpts + fill ----------------
__global__ __launch_bounds__(256) void mega_kernel(
    // qqp gemm
    const float* __restrict__ frame_s, const float* __restrict__ wqqpT,
    const float* __restrict__ bqqp, float* __restrict__ qqp, int n,
    // k gemm
    const float* __restrict__ tfn, const float* __restrict__ wksT,
    float* __restrict__ kbuf,
    // kpts
    const float* __restrict__ Wkv, float* __restrict__ kpts,
    // fill (CSR elist build)
    const int* __restrict__ srcA, int* __restrict__ cur, int* __restrict__ elist, int E,
    // block partition
    int nb_qqp_x, int nb_qqp, int nb_k, int nb_kpts)
{
    __shared__ unsigned short As[128 * 72];
    __shared__ unsigned short Bs[128 * 72];
    int b = blockIdx.x;
    if (b < nb_qqp) {         // [q | qp_raw] = frame_s @ [Wq|Wqp] + bias  (N=320, WJ=4)
        gemm_body<4>(As, Bs, frame_s, 384, wqqpT, 384, bqqp, qqp, 320, n, 320, 384,
                     b % nb_qqp_x, b / nb_qqp_x);
        return;
    }
    b -= nb_qqp;
    if (b < nb_k) {           // k = tfn[:, :128] @ Wk_s  (N=128, WJ=4)
        gemm_body<4>(As, Bs, tfn, 176, wksT, 128, nullptr, kbuf, 128, n, 128, 128, b, 0);
        return;
    }
    b -= nb_k;
    if (b < nb_kpts) {        // k_pts
        int t = b * 256 + threadIdx.x;
        if (t < n * 24) {
            int node = t / 24, f = t % 24;
            int a = f >> 3;
            int bb2 = f & 7;
            const float* vr = tfn + (size_t)node * 176 + 128;
            float s = 0.f;
            #pragma unroll
            for (int p = 0; p < 16; ++p) s += vr[p * 3 + a] * Wkv[p * 8 + bb2];
            kpts[t] = s;
        }
        return;
    }
    b -= nb_kpts;
    {                         // fill: CSR edge list
        int e = b * 256 + threadIdx.x;
        if (e < E) {
            int s = srcA[e];
            int pos = atomicAdd(&cur[s], 1);
            elist[pos] = e;
        }
    }
}

// ---------------- prep: transpose/concat weights, fold logit scales, zero cnt ----------------
__global__ void prep_kernel(const float* __restrict__ Wq, const float* __restrict__ bq,
                            const float* __restrict__ Wqp, const float* __restrict__ bqp,
                            const float* __restrict__ Wb, const float* __restrict__ bb,
                            const float* __restrict__ Wdz, const float* __restrict__ bdz,
                            const float* __restrict__ Wks, const float* __restrict__ Wout,
                            float* __restrict__ wqqpT, float* __restrict__ bqqp,
                            float* __restrict__ wcatT, float* __restrict__ bcat,
                            float* __restrict__ wksT, float* __restrict__ woutT,
                            int* __restrict__ cnt, int n)
{
    const float SC_QK = 0.14433756729740643f;   // sqrt(1/48), folded into q
    const float SC_B  = 0.5773502691896258f;    // sqrt(1/3), folded into b
    int gid = blockIdx.x * 256 + threadIdx.x;
    int stride = gridDim.x * 256;
    for (int i = gid; i < n; i += stride) cnt[i] = 0;
    for (int i = gid; i < 320 * 384; i += stride) {
        int o = i / 384, c = i % 384;
        wqqpT[i] = (o < 128) ? Wq[c * 128 + o] * SC_QK : Wqp[c * 192 + (o - 128)];
    }
    for (int i = gid; i < 320; i += stride) bqqp[i] = (i < 128) ? bq[i] * SC_QK : bqp[i - 128];
    for (int i = gid; i < 40 * 128; i += stride) {
        int o = i >> 7, c = i & 127;
        wcatT[i] = (o < 8) ? Wb[c * 8 + o] * SC_B : Wdz[c * 32 + (o - 8)];
    }
    for (int i = gid; i < 40; i += stride) bcat[i] = (i < 8) ? bb[i] * SC_B : bdz[i - 8];
    for (int i = gid; i < 128 * 128; i += stride) {
        int o = i >> 7, c = i & 127;
        wksT[i] = Wks[c * 128 + o];
    }
    for (int i = gid; i < 384 * 416; i += stride) {
        int o = i / 416, c = i % 416;
        woutT[i] = Wout[c * 384 + o];
    }
}

// ---------------- CSR build ----------------
__global__ void count_kernel(const int* __restrict__ srcA, int* __restrict__ cnt, int E)
{
    int e = blockIdx.x * 256 + threadIdx.x;
    if (e < E) atomicAdd(&cnt[srcA[e]], 1);
}

__global__ void scan_kernel(const int* __restrict__ cnt, int* __restrict__ off,
                            int* __restrict__ cur, int n)
{
    __shared__ int sums[1024];
    int t = threadIdx.x;
    int chunk = (n + 1023) >> 10;
    int begin = t * chunk;
    int local = 0;
    for (int j = 0; j < chunk; ++j) {
        int i = begin + j;
        if (i < n) local += cnt[i];
    }
    sums[t] = local;
    __syncthreads();
    for (int d = 1; d < 1024; d <<= 1) {
        int x = sums[t];
        int y = (t >= d) ? sums[t - d] : 0;
        __syncthreads();
        sums[t] = x + y;
        __syncthreads();
    }
    int run = sums[t] - local;
    for (int j = 0; j < chunk; ++j) {
        int i = begin + j;
        if (i < n) {
            off[i] = run;
            cur[i] = run;
            run += cnt[i];
        }
    }
}

// ---------------- attention + aggregation + finalize (qpts computed inline) ----------------
// lane = es*8 + h : es = edge slot (0..7), h = head (0..7)
__global__ __launch_bounds__(256) void attn_kernel(
    const int* __restrict__ off, const int* __restrict__ cnt,
    const int* __restrict__ elist, const int* __restrict__ dstA,
    const float* __restrict__ qqp, const float* __restrict__ kbuf,
    const float* __restrict__ kpts,
    const float* __restrict__ bpair, const float* __restrict__ mask,
    const float* __restrict__ hwin,
    const float* __restrict__ rot, const float* __restrict__ trans,
    float* __restrict__ feats, int n)
{
    int wave = threadIdx.x >> 6;
    int lane = threadIdx.x & 63;
    int s = blockIdx.x * 4 + wave;
    if (s >= n) return;
    int es = lane >> 3;
    int h  = lane & 7;

    float qh[16];
    {
        const float* qp = qqp + (size_t)s * 320 + h * 16;
        #pragma unroll
        for (int c = 0; c < 16; ++c) qh[c] = qp[c];
    }
    // rotation + translation (also reused in epilogue)
    const float* Rp = rot + (size_t)s * 9;
    const float* Tp = trans + (size_t)s * 3;
    float R0 = Rp[0], R1 = Rp[1], R2 = Rp[2];
    float R3 = Rp[3], R4 = Rp[4], R5 = Rp[5];
    float R6 = Rp[6], R7 = Rp[7], R8 = Rp[8];
    float T0 = Tp[0], T1 = Tp[1], T2 = Tp[2];
    // q_pts for head h, computed inline
    float qpt[24];
    {
        const float* qr = qqp + (size_t)s * 320 + 128 + h * 8;
        #pragma unroll
        for (int p2 = 0; p2 < 8; ++p2) {
            float c0 = qr[p2], c1 = qr[64 + p2], c2 = qr[128 + p2];
            qpt[p2 * 3 + 0] = R0 * c0 + R1 * c1 + R2 * c2 + T0;
            qpt[p2 * 3 + 1] = R3 * c0 + R4 * c1 + R5 * c2 + T1;
            qpt[p2 * 3 + 2] = R6 * c0 + R7 * c1 + R8 * c2 + T2;
        }
    }
    // softplus(hw) * sqrt(1/108) * 0.5 folded together
    float hwv = log1pf(__expf(hwin[h])) * 0.04811252243246882f;
    float mask_s = mask[s];
    int myoff = off[s], mycnt = cnt[s];

    float ssum = 0.f;
    float oacc[16];
    #pragma unroll
    for (int c = 0; c < 16; ++c) oacc[c] = 0.f;
    float optacc[3] = {0.f, 0.f, 0.f};
    float opacc[8][4];
    #pragma unroll
    for (int j = 0; j < 8; ++j)
        #pragma unroll
        for (int c = 0; c < 4; ++c) opacc[j][c] = 0.f;

    int nb = (mycnt + 7) >> 3;
    for (int b = 0; b < nb; ++b) {
        int idx = b * 8 + es;
        bool valid = idx < mycnt;
        int e = valid ? elist[myoff + idx] : 0;
        int d = dstA[e];

        const float* kr = kbuf + (size_t)d * 128 + h * 16;
        float4 ka = *(const float4*)(kr + 0);
        float4 kb = *(const float4*)(kr + 4);
        float4 kc = *(const float4*)(kr + 8);
        float4 kd = *(const float4*)(kr + 12);

        const float* kp = kpts + (size_t)d * 24 + h * 3;
        float kp0 = kp[0], kp1 = kp[1], kp2 = kp[2];

        const float* bp = bpair + (size_t)e * 40;
        float bh = bp[h];
        float4 pair4 = *(const float4*)(bp + 8 + h * 4);

        float qk = qh[0] * ka.x + qh[1] * ka.y + qh[2] * ka.z + qh[3] * ka.w
                 + qh[4] * kb.x + qh[5] * kb.y + qh[6] * kb.z + qh[7] * kb.w
                 + qh[8] * kc.x + qh[9] * kc.y + qh[10] * kc.z + qh[11] * kc.w
                 + qh[12] * kd.x + qh[13] * kd.y + qh[14] * kd.z + qh[15] * kd.w;

        float pt = 0.f;
        #pragma unroll
        for (int pp = 0; pp < 8; ++pp) {
            float d0 = qpt[pp * 3 + 0] - kp0;
            float d1 = qpt[pp * 3 + 1] - kp1;
            float d2 = qpt[pp * 3 + 2] - kp2;
            pt += d0 * d0 + d1 * d1 + d2 * d2;
        }

        float md = mask[d];
        // qk and bh arrive pre-scaled (folded into weights at prep)
        float logit = qk + bh - hwv * pt + 100000.0f * (mask_s * md - 1.0f);
        float w = valid ? __expf(logit) : 0.f;

        ssum += w;
        oacc[0] += w * ka.x; oacc[1] += w * ka.y; oacc[2] += w * ka.z; oacc[3] += w * ka.w;
        oacc[4] += w * kb.x; oacc[5] += w * kb.y; oacc[6] += w * kb.z; oacc[7] += w * kb.w;
        oacc[8] += w * kc.x; oacc[9] += w * kc.y; oacc[10] += w * kc.z; oacc[11] += w * kc.w;
        oacc[12] += w * kd.x; oacc[13] += w * kd.y; oacc[14] += w * kd.z; oacc[15] += w * kd.w;
        optacc[0] += w * kp0;
        optacc[1] += w * kp1;
        optacc[2] += w * kp2;

        // o_pair: pair_z is head-independent -> broadcast w (1 shuffle per target head).
        #pragma unroll
        for (int jh = 0; jh < 8; ++jh) {
            float wj = __shfl(w, (es << 3) + jh);
            opacc[jh][0] += wj * pair4.x;
            opacc[jh][1] += wj * pair4.y;
            opacc[jh][2] += wj * pair4.z;
            opacc[jh][3] += wj * pair4.w;
        }
    }

    // reduce across the 8 edge slots (lane bits 3..5)
    #pragma unroll
    for (int delta = 8; delta <= 32; delta <<= 1) {
        ssum += __shfl_xor(ssum, delta);
        #pragma unroll
        for (int c = 0; c < 16; ++c) oacc[c] += __shfl_xor(oacc[c], delta);
        #pragma unroll
        for (int i = 0; i < 3; ++i) optacc[i] += __shfl_xor(optacc[i], delta);
        #pragma unroll
        for (int j = 0; j < 8; ++j)
            #pragma unroll
            for (int c = 0; c < 4; ++c) opacc[j][c] += __shfl_xor(opacc[j][c], delta);
    }

    // Per-head denominators for o_pair (opacc[jh] used head jh's weights).
    float invj[8];
    #pragma unroll
    for (int jh = 0; jh < 8; ++jh)
        invj[jh] = 1.f / (__shfl(ssum, jh) + 1e-16f);

    if (es == 0) {
        float inv = 1.f / (ssum + 1e-16f);
        float* f = feats + (size_t)s * 416;
        // o -> f[0:128]
        #pragma unroll
        for (int c = 0; c < 16; c += 4) {
            float4 v = make_float4(oacc[c] * inv, oacc[c + 1] * inv, oacc[c + 2] * inv, oacc[c + 3] * inv);
            *(float4*)(&f[h * 16 + c]) = v;
        }
        // o_pt rotate back + norm -> f[128:160] (R,T already in registers)
        float v0 = optacc[0] * inv - T0;
        float v1 = optacc[1] * inv - T1;
        float v2 = optacc[2] * inv - T2;
        float r0 = R0 * v0 + R3 * v1 + R6 * v2;
        float r1 = R1 * v0 + R4 * v1 + R7 * v2;
        float r2 = R2 * v0 + R5 * v1 + R8 * v2;
        f[128 + h] = r0;
        f[136 + h] = r1;
        f[144 + h] = r2;
        f[152 + h] = sqrtf(r0 * r0 + r1 * r1 + r2 * r2 + 1e-8f);
        // o_pair -> f[160:416]
        #pragma unroll
        for (int jh = 0; jh < 8; ++jh) {
            float4 v = make_float4(opacc[jh][0] * invj[jh], opacc[jh][1] * invj[jh],
                                   opacc[jh][2] * invj[jh], opacc[jh][3] * invj[jh]);
            *(float4*)(&f[160 + jh * 32 + h * 4]) = v;
        }
    }
}

// ---------------- host ----------------
extern "C" void kernel_launch(void* const* d_in, const int* in_sizes, int n_in,
                              void* d_out, int out_size, void* d_ws, size_t ws_size,
                              hipStream_t stream)
{
    const float* frame_s = (const float*)d_in[0];
    const float* tfn     = (const float*)d_in[1];
    const float* z       = (const float*)d_in[2];
    const int*   ei      = (const int*)d_in[3];
    const float* mask    = (const float*)d_in[4];
    const float* rot     = (const float*)d_in[5];
    const float* trans   = (const float*)d_in[6];
    const float* Wq      = (const float*)d_in[7];
    const float* bq      = (const float*)d_in[8];
    const float* Wks     = (const float*)d_in[9];
    const float* Wkv     = (const float*)d_in[10];
    const float* Wqp     = (const float*)d_in[11];
    const float* bqp     = (const float*)d_in[12];
    const float* Wb      = (const float*)d_in[13];
    const float* bb      = (const float*)d_in[14];
    const float* Wdz     = (const float*)d_in[15];
    const float* bdz     = (const float*)d_in[16];
    const float* hw      = (const float*)d_in[17];
    const float* Wout    = (const float*)d_in[18];
    const float* bout    = (const float*)d_in[19];
    float* out = (float*)d_out;

    int n = in_sizes[0] / 384;
    int E = in_sizes[3] / 2;
    const int* dstA = ei;        // edge_index[0]
    const int* srcA = ei + E;    // edge_index[1]

    float* ws = (float*)d_ws;
    size_t p = 0;
    auto alloc = [&](size_t elems) -> float* {
        float* r = ws + p;
        p += (elems + 15) & ~((size_t)15);
        return r;
    };
    float* qqpbuf = alloc((size_t)n * 320);   // [q | qp_raw]
    float* kbuf   = alloc((size_t)n * 128);
    float* kpts   = alloc((size_t)n * 24);
    float* feats  = alloc((size_t)n * 416);
    float* bpair  = alloc((size_t)E * 40);    // edge order, sequential write
    float* wqqpT  = alloc(320 * 384);
    float* bqqp   = alloc(320);
    float* wcatT  = alloc(40 * 128);
    float* bcat   = alloc(64);
    float* wksT   = alloc(128 * 128);
    float* woutT  = alloc(384 * 416);
    int* cnt   = (int*)alloc((size_t)n);
    int* off   = (int*)alloc((size_t)n);
    int* cur   = (int*)alloc((size_t)n);
    int* elist = (int*)alloc((size_t)E);

    prep_kernel<<<512, 256, 0, stream>>>(Wq, bq, Wqp, bqp, Wb, bb, Wdz, bdz, Wks, Wout,
                                         wqqpT, bqqp, wcatT, bcat, wksT, woutT, cnt, n);

    count_kernel<<<(E + 255) / 256, 256, 0, stream>>>(srcA, cnt, E);
    scan_kernel<<<1, 1024, 0, stream>>>(cnt, off, cur, n);

    // bpair = z @ [Wb|Wdz] + bias : zero-LDS register-resident streaming GEMM
    bpair_stream<<<2048, 256, 0, stream>>>(z, wcatT, bcat, bpair, E);

    // mega2: qqp GEMM + k GEMM + kpts + fill
    int nb_qqp_x = (n + 127) / 128;
    int nb_qqp   = nb_qqp_x * 3;              // N=320 -> 3 tiles of 128 (GBN=128, WJ=4)
    int nb_k     = (n + 127) / 128;
    int nb_kpts  = (n * 24 + 255) / 256;
    int nb_fill  = (E + 255) / 256;
    int nb_total = nb_qqp + nb_k + nb_kpts + nb_fill;
    mega_kernel<<<nb_total, 256, 0, stream>>>(
        frame_s, wqqpT, bqqp, qqpbuf, n,
        tfn, wksT, kbuf,
        Wkv, kpts,
        srcA, cur, elist, E,
        nb_qqp_x, nb_qqp, nb_k, nb_kpts);

    attn_kernel<<<(n + 3) / 4, 256, 0, stream>>>(off, cnt, elist, dstA,
                                                 qqpbuf, kbuf, kpts, bpair, mask, hw,
                                                 rot, trans, feats, n);

    {   // out = feats @ Wout + bout
        dim3 g((n + 127) / 128, 3);
        gemm_mfma<4><<<g, 256, 0, stream>>>(feats, 416, woutT, 416, bout, out, 384, n, 384, 416);
    }
    (void)n_in; (void)out_size; (void)ws_size;
}

// Round 5
// 815.620 us; speedup vs baseline: 1.1852x; 1.0507x over previous
//
#include <hip/hip_runtime.h>
#include <math.h>

typedef __attribute__((ext_vector_type(8))) short short8;
typedef __attribute__((ext_vector_type(4))) float f32x4;

static __device__ inline unsigned short f2bf(float f) {
    union { float f; unsigned u; } v; v.f = f;
    unsigned r = v.u + 0x7FFF + ((v.u >> 16) & 1);
    return (unsigned short)(r >> 16);
}

// ---------------- MFMA bf16 GEMM body: C[M,N] = A[M,K] @ BT[N,K]^T + bias ----------------
// Block tile: 128 x (WJ*32), BK=64. 4 waves in 2x2. Wave tile: 64 x (WJ*16).
template<int WJ>
__device__ __forceinline__ void gemm_body(
    unsigned short* __restrict__ As, unsigned short* __restrict__ Bs,
    const float* __restrict__ A, int lda,
    const float* __restrict__ BT, int ldb,   // BT is [N][K] row-major
    const float* __restrict__ bias,
    float* __restrict__ C, int ldc,
    int M, int N, int K, int bx, int by)
{
    constexpr int GBN = WJ * 32;
    const int t = threadIdx.x;
    const int wid = t >> 6, lane = t & 63;
    const int wm = (wid & 1) * 64;
    const int wn = (wid >> 1) * (WJ * 16);
    const int row16 = lane & 15, quad = lane >> 4;
    const int bm = bx * 128;
    const int bn = by * GBN;

    f32x4 acc[4][WJ];
    #pragma unroll
    for (int i = 0; i < 4; ++i)
        #pragma unroll
        for (int j = 0; j < WJ; ++j)
            #pragma unroll
            for (int r = 0; r < 4; ++r) acc[i][j][r] = 0.f;

    const int ktiles = (K + 63) >> 6;
    for (int kt = 0; kt < ktiles; ++kt) {
        const int k0 = kt << 6;
        // stage A: 128 rows x 64 k
        #pragma unroll
        for (int it = 0; it < 8; ++it) {
            int f = it * 256 + t;
            int row = f >> 4, kq = (f & 15) << 2;
            float4 av = make_float4(0.f, 0.f, 0.f, 0.f);
            if (bm + row < M && k0 + kq < K)
                av = *(const float4*)(A + (size_t)(bm + row) * lda + k0 + kq);
            ushort4 uv;
            uv.x = f2bf(av.x); uv.y = f2bf(av.y); uv.z = f2bf(av.z); uv.w = f2bf(av.w);
            *(ushort4*)(&As[row * 72 + kq]) = uv;
        }
        // stage B: GBN rows x 64 k
        #pragma unroll
        for (int it = 0; it < WJ * 2; ++it) {
            int f = it * 256 + t;
            int row = f >> 4, kq = (f & 15) << 2;
            float4 bv = make_float4(0.f, 0.f, 0.f, 0.f);
            if (bn + row < N && k0 + kq < K)
                bv = *(const float4*)(BT + (size_t)(bn + row) * ldb + k0 + kq);
            ushort4 uv;
            uv.x = f2bf(bv.x); uv.y = f2bf(bv.y); uv.z = f2bf(bv.z); uv.w = f2bf(bv.w);
            *(ushort4*)(&Bs[row * 72 + kq]) = uv;
        }
        __syncthreads();

        #pragma unroll
        for (int ks = 0; ks < 64; ks += 32) {
            short8 af[4], bfv[WJ];
            #pragma unroll
            for (int i = 0; i < 4; ++i)
                af[i] = *(const short8*)(&As[(wm + i * 16 + row16) * 72 + ks + quad * 8]);
            #pragma unroll
            for (int j = 0; j < WJ; ++j)
                bfv[j] = *(const short8*)(&Bs[(wn + j * 16 + row16) * 72 + ks + quad * 8]);
            #pragma unroll
            for (int i = 0; i < 4; ++i)
                #pragma unroll
                for (int j = 0; j < WJ; ++j)
                    acc[i][j] = __builtin_amdgcn_mfma_f32_16x16x32_bf16(af[i], bfv[j], acc[i][j], 0, 0, 0);
        }
        __syncthreads();
    }

    #pragma unroll
    for (int i = 0; i < 4; ++i)
        #pragma unroll
        for (int j = 0; j < WJ; ++j) {
            int col = bn + wn + j * 16 + row16;
            if (col >= N) continue;
            float bv = bias ? bias[col] : 0.f;
            #pragma unroll
            for (int r = 0; r < 4; ++r) {
                int row = bm + wm + i * 16 + quad * 4 + r;
                if (row < M) C[(size_t)row * ldc + col] = acc[i][j][r] + bv;
            }
        }
}

template<int WJ>
__global__ __launch_bounds__(256) void gemm_mfma(
    const float* __restrict__ A, int lda,
    const float* __restrict__ BT, int ldb,
    const float* __restrict__ bias,
    float* __restrict__ C, int ldc,
    int M, int N, int K)
{
    __shared__ unsigned short As[128 * 72];
    __shared__ unsigned short Bs[WJ * 32 * 72];
    gemm_body<WJ>(As, Bs, A, lda, BT, ldb, bias, C, ldc, M, N, K, blockIdx.x, blockIdx.y);
}

// ---------------- bpair streaming GEMM body: N=40, K=128, B held in registers ----------------
// Zero LDS, zero __syncthreads. Each wave streams 32-row strips of z:
// 16 independent float4 loads -> cvt -> 24 MFMA -> store. Pure HBM stream.
__device__ __forceinline__ void bpair_body(
    const float* __restrict__ z, const float* __restrict__ wcatT,
    const float* __restrict__ bcat, float* __restrict__ bpair, int E,
    int bb, int nbb)
{
    const int lane = threadIdx.x & 63;
    const int wid = threadIdx.x >> 6;
    const int row16 = lane & 15, quad = lane >> 4;

    // Preload B fragments (whole 40x128 weight) + bias into registers.
    short8 bfv[3][4];
    float bj[3];
    #pragma unroll
    for (int j = 0; j < 3; ++j) {
        int col = j * 16 + row16;
        bool cv = col < 40;
        bj[j] = cv ? bcat[col] : 0.f;
        #pragma unroll
        for (int ks = 0; ks < 4; ++ks) {
            float4 w0 = make_float4(0.f, 0.f, 0.f, 0.f);
            float4 w1 = make_float4(0.f, 0.f, 0.f, 0.f);
            if (cv) {
                const float* wp = wcatT + (size_t)col * 128 + ks * 32 + quad * 8;
                w0 = *(const float4*)(wp);
                w1 = *(const float4*)(wp + 4);
            }
            short8 f;
            f[0] = (short)f2bf(w0.x); f[1] = (short)f2bf(w0.y);
            f[2] = (short)f2bf(w0.z); f[3] = (short)f2bf(w0.w);
            f[4] = (short)f2bf(w1.x); f[5] = (short)f2bf(w1.y);
            f[6] = (short)f2bf(w1.z); f[7] = (short)f2bf(w1.w);
            bfv[j][ks] = f;
        }
    }

    const int nstrips = (E + 31) >> 5;
    const int gw = bb * 4 + wid;
    const int nw = nbb * 4;
    for (int st = gw; st < nstrips; st += nw) {
        const int r0 = st * 32;
        short8 af[2][4];
        #pragma unroll
        for (int i = 0; i < 2; ++i) {
            int row = r0 + i * 16 + row16;
            bool rv = row < E;
            const float* zp = z + (size_t)row * 128 + quad * 8;
            #pragma unroll
            for (int ks = 0; ks < 4; ++ks) {
                float4 a0 = make_float4(0.f, 0.f, 0.f, 0.f);
                float4 a1 = make_float4(0.f, 0.f, 0.f, 0.f);
                if (rv) {
                    a0 = *(const float4*)(zp + ks * 32);
                    a1 = *(const float4*)(zp + ks * 32 + 4);
                }
                short8 f;
                f[0] = (short)f2bf(a0.x); f[1] = (short)f2bf(a0.y);
                f[2] = (short)f2bf(a0.z); f[3] = (short)f2bf(a0.w);
                f[4] = (short)f2bf(a1.x); f[5] = (short)f2bf(a1.y);
                f[6] = (short)f2bf(a1.z); f[7] = (short)f2bf(a1.w);
                af[i][ks] = f;
            }
        }

        f32x4 acc[2][3];
        #pragma unroll
        for (int i = 0; i < 2; ++i)
            #pragma unroll
            for (int j = 0; j < 3; ++j)
                #pragma unroll
                for (int r = 0; r < 4; ++r) acc[i][j][r] = 0.f;

        #pragma unroll
        for (int ks = 0; ks < 4; ++ks)
            #pragma unroll
            for (int i = 0; i < 2; ++i)
                #pragma unroll
                for (int j = 0; j < 3; ++j)
                    acc[i][j] = __builtin_amdgcn_mfma_f32_16x16x32_bf16(af[i][ks], bfv[j][ks], acc[i][j], 0, 0, 0);

        #pragma unroll
        for (int i = 0; i < 2; ++i)
            #pragma unroll
            for (int j = 0; j < 3; ++j) {
                int col = j * 16 + row16;
                if (col >= 40) continue;
                #pragma unroll
                for (int r = 0; r < 4; ++r) {
                    int row = r0 + i * 16 + quad * 4 + r;
                    if (row < E) bpair[(size_t)row * 40 + col] = acc[i][j][r] + bj[j];
                }
            }
    }
}

// ---------------- mega: bpair + qqp GEMM + k GEMM + kpts + fill, one launch ----------------
// bpair's 2048 grid-stride blocks provide the TLP that hides the skinny GEMMs'
// barrier-drain latency; everything packs into one dispatch.
__global__ __launch_bounds__(256) void mega_kernel(
    const float* __restrict__ z, const float* __restrict__ wcatT,
    const float* __restrict__ bcat, float* __restrict__ bpair, int E,
    const float* __restrict__ frame_s, const float* __restrict__ wqqpT,
    const float* __restrict__ bqqp, float* __restrict__ qqp, int n,
    const float* __restrict__ tfn, const float* __restrict__ wksT,
    float* __restrict__ kbuf,
    const float* __restrict__ Wkv, float* __restrict__ kpts,
    const int* __restrict__ srcA, const int* __restrict__ dstA,
    int* __restrict__ cur, int2* __restrict__ einfo,
    int nb_bp, int nb_qqp_x, int nb_qqp, int nb_k, int nb_kpts)
{
    __shared__ unsigned short As[128 * 72];
    __shared__ unsigned short Bs[128 * 72];
    int b = blockIdx.x;
    if (b < nb_bp) {          // bpair = z @ [Wb|Wdz] + bias (register-B streaming)
        bpair_body(z, wcatT, bcat, bpair, E, b, nb_bp);
        return;
    }
    b -= nb_bp;
    if (b < nb_qqp) {         // [q | qp_raw] = frame_s @ [Wq|Wqp] + bias  (N=320, WJ=4)
        gemm_body<4>(As, Bs, frame_s, 384, wqqpT, 384, bqqp, qqp, 320, n, 320, 384,
                     b % nb_qqp_x, b / nb_qqp_x);
        return;
    }
    b -= nb_qqp;
    if (b < nb_k) {           // k = tfn[:, :128] @ Wk_s  (N=128, WJ=4)
        gemm_body<4>(As, Bs, tfn, 176, wksT, 128, nullptr, kbuf, 128, n, 128, 128, b, 0);
        return;
    }
    b -= nb_k;
    if (b < nb_kpts) {        // k_pts
        int t = b * 256 + threadIdx.x;
        if (t < n * 24) {
            int node = t / 24, f = t % 24;
            int a = f >> 3;
            int bb2 = f & 7;
            const float* vr = tfn + (size_t)node * 176 + 128;
            float s = 0.f;
            #pragma unroll
            for (int p = 0; p < 16; ++p) s += vr[p * 3 + a] * Wkv[p * 8 + bb2];
            kpts[t] = s;
        }
        return;
    }
    b -= nb_kpts;
    {                         // fill: CSR edge list with fused (e, dst) records
        int e = b * 256 + threadIdx.x;
        if (e < E) {
            int s = srcA[e];
            int pos = atomicAdd(&cur[s], 1);
            einfo[pos] = make_int2(e, dstA[e]);
        }
    }
}

// ---------------- prep (+count fused): transpose/concat weights, fold scales, count ----------------
// cnt must be zeroed (hipMemsetAsync) before this kernel.
__global__ void prep_count_kernel(
    const float* __restrict__ Wq, const float* __restrict__ bq,
    const float* __restrict__ Wqp, const float* __restrict__ bqp,
    const float* __restrict__ Wb, const float* __restrict__ bb,
    const float* __restrict__ Wdz, const float* __restrict__ bdz,
    const float* __restrict__ Wks, const float* __restrict__ Wout,
    float* __restrict__ wqqpT, float* __restrict__ bqqp,
    float* __restrict__ wcatT, float* __restrict__ bcat,
    float* __restrict__ wksT, float* __restrict__ woutT,
    const int* __restrict__ srcA, int* __restrict__ cnt, int E, int nb_cnt)
{
    int b = blockIdx.x;
    if (b < nb_cnt) {         // degree count
        int e = b * 256 + threadIdx.x;
        if (e < E) atomicAdd(&cnt[srcA[e]], 1);
        return;
    }
    b -= nb_cnt;
    const float SC_QK = 0.14433756729740643f;   // sqrt(1/48), folded into q
    const float SC_B  = 0.5773502691896258f;    // sqrt(1/3), folded into b
    int gid = b * 256 + threadIdx.x;
    int stride = (gridDim.x - nb_cnt) * 256;
    for (int i = gid; i < 320 * 384; i += stride) {
        int o = i / 384, c = i % 384;
        wqqpT[i] = (o < 128) ? Wq[c * 128 + o] * SC_QK : Wqp[c * 192 + (o - 128)];
    }
    for (int i = gid; i < 320; i += stride) bqqp[i] = (i < 128) ? bq[i] * SC_QK : bqp[i - 128];
    for (int i = gid; i < 40 * 128; i += stride) {
        int o = i >> 7, c = i & 127;
        wcatT[i] = (o < 8) ? Wb[c * 8 + o] * SC_B : Wdz[c * 32 + (o - 8)];
    }
    for (int i = gid; i < 40; i += stride) bcat[i] = (i < 8) ? bb[i] * SC_B : bdz[i - 8];
    for (int i = gid; i < 128 * 128; i += stride) {
        int o = i >> 7, c = i & 127;
        wksT[i] = Wks[c * 128 + o];
    }
    for (int i = gid; i < 384 * 416; i += stride) {
        int o = i / 416, c = i % 416;
        woutT[i] = Wout[c * 384 + o];
    }
}

// ---------------- CSR scan ----------------
__global__ void scan_kernel(const int* __restrict__ cnt, int* __restrict__ off,
                            int* __restrict__ cur, int n)
{
    __shared__ int sums[1024];
    int t = threadIdx.x;
    int chunk = (n + 1023) >> 10;
    int begin = t * chunk;
    int local = 0;
    for (int j = 0; j < chunk; ++j) {
        int i = begin + j;
        if (i < n) local += cnt[i];
    }
    sums[t] = local;
    __syncthreads();
    for (int d = 1; d < 1024; d <<= 1) {
        int x = sums[t];
        int y = (t >= d) ? sums[t - d] : 0;
        __syncthreads();
        sums[t] = x + y;
        __syncthreads();
    }
    int run = sums[t] - local;
    for (int j = 0; j < chunk; ++j) {
        int i = begin + j;
        if (i < n) {
            off[i] = run;
            cur[i] = run;
            run += cnt[i];
        }
    }
}

// ---------------- attention + aggregation + finalize (qpts inline, einfo pipelined) ----------------
// lane = es*8 + h : es = edge slot (0..7), h = head (0..7)
__global__ __launch_bounds__(256) void attn_kernel(
    const int* __restrict__ off, const int* __restrict__ cnt,
    const int2* __restrict__ einfo,
    const float* __restrict__ qqp, const float* __restrict__ kbuf,
    const float* __restrict__ kpts,
    const float* __restrict__ bpair, const float* __restrict__ mask,
    const float* __restrict__ hwin,
    const float* __restrict__ rot, const float* __restrict__ trans,
    float* __restrict__ feats, int n)
{
    int wave = threadIdx.x >> 6;
    int lane = threadIdx.x & 63;
    int s = blockIdx.x * 4 + wave;
    if (s >= n) return;
    int es = lane >> 3;
    int h  = lane & 7;

    float qh[16];
    {
        const float* qp = qqp + (size_t)s * 320 + h * 16;
        #pragma unroll
        for (int c = 0; c < 16; ++c) qh[c] = qp[c];
    }
    // rotation + translation (also reused in epilogue)
    const float* Rp = rot + (size_t)s * 9;
    const float* Tp = trans + (size_t)s * 3;
    float R0 = Rp[0], R1 = Rp[1], R2 = Rp[2];
    float R3 = Rp[3], R4 = Rp[4], R5 = Rp[5];
    float R6 = Rp[6], R7 = Rp[7], R8 = Rp[8];
    float T0 = Tp[0], T1 = Tp[1], T2 = Tp[2];
    // q_pts for head h, computed inline
    float qpt[24];
    {
        const float* qr = qqp + (size_t)s * 320 + 128 + h * 8;
        #pragma unroll
        for (int p2 = 0; p2 < 8; ++p2) {
            float c0 = qr[p2], c1 = qr[64 + p2], c2 = qr[128 + p2];
            qpt[p2 * 3 + 0] = R0 * c0 + R1 * c1 + R2 * c2 + T0;
            qpt[p2 * 3 + 1] = R3 * c0 + R4 * c1 + R5 * c2 + T1;
            qpt[p2 * 3 + 2] = R6 * c0 + R7 * c1 + R8 * c2 + T2;
        }
    }
    // softplus(hw) * sqrt(1/108) * 0.5 folded together
    float hwv = log1pf(__expf(hwin[h])) * 0.04811252243246882f;
    float mask_s = mask[s];
    int myoff = off[s], mycnt = cnt[s];

    float ssum = 0.f;
    float oacc[16];
    #pragma unroll
    for (int c = 0; c < 16; ++c) oacc[c] = 0.f;
    float optacc[3] = {0.f, 0.f, 0.f};
    float opacc[8][4];
    #pragma unroll
    for (int j = 0; j < 8; ++j)
        #pragma unroll
        for (int c = 0; c < 4; ++c) opacc[j][c] = 0.f;

    int nb = (mycnt + 7) >> 3;
    // software-pipelined (e,d) record: one iteration ahead
    int2 ed = make_int2(0, 0);
    if (nb > 0) {
        int pos0 = (es < mycnt) ? myoff + es : (mycnt > 0 ? myoff : 0);
        ed = einfo[pos0];
    }
    for (int b = 0; b < nb; ++b) {
        int idx = b * 8 + es;
        bool valid = idx < mycnt;
        int e = ed.x, d = ed.y;
        // prefetch next iteration's record (wave-uniform branch)
        int2 ned = ed;
        if (b + 1 < nb) {
            int nidx = idx + 8;
            int npos = (nidx < mycnt) ? myoff + nidx : myoff;
            ned = einfo[npos];
        }

        const float* kr = kbuf + (size_t)d * 128 + h * 16;
        float4 ka = *(const float4*)(kr + 0);
        float4 kb = *(const float4*)(kr + 4);
        float4 kc = *(const float4*)(kr + 8);
        float4 kd = *(const float4*)(kr + 12);

        const float* kp = kpts + (size_t)d * 24 + h * 3;
        float kp0 = kp[0], kp1 = kp[1], kp2 = kp[2];

        const float* bp = bpair + (size_t)e * 40;
        float bh = bp[h];
        float4 pair4 = *(const float4*)(bp + 8 + h * 4);

        float qk = qh[0] * ka.x + qh[1] * ka.y + qh[2] * ka.z + qh[3] * ka.w
                 + qh[4] * kb.x + qh[5] * kb.y + qh[6] * kb.z + qh[7] * kb.w
                 + qh[8] * kc.x + qh[9] * kc.y + qh[10] * kc.z + qh[11] * kc.w
                 + qh[12] * kd.x + qh[13] * kd.y + qh[14] * kd.z + qh[15] * kd.w;

        float pt = 0.f;
        #pragma unroll
        for (int pp = 0; pp < 8; ++pp) {
            float d0 = qpt[pp * 3 + 0] - kp0;
            float d1 = qpt[pp * 3 + 1] - kp1;
            float d2 = qpt[pp * 3 + 2] - kp2;
            pt += d0 * d0 + d1 * d1 + d2 * d2;
        }

        float md = mask[d];
        // qk and bh arrive pre-scaled (folded into weights at prep)
        float logit = qk + bh - hwv * pt + 100000.0f * (mask_s * md - 1.0f);
        float w = valid ? __expf(logit) : 0.f;

        ssum += w;
        oacc[0] += w * ka.x; oacc[1] += w * ka.y; oacc[2] += w * ka.z; oacc[3] += w * ka.w;
        oacc[4] += w * kb.x; oacc[5] += w * kb.y; oacc[6] += w * kb.z; oacc[7] += w * kb.w;
        oacc[8] += w * kc.x; oacc[9] += w * kc.y; oacc[10] += w * kc.z; oacc[11] += w * kc.w;
        oacc[12] += w * kd.x; oacc[13] += w * kd.y; oacc[14] += w * kd.z; oacc[15] += w * kd.w;
        optacc[0] += w * kp0;
        optacc[1] += w * kp1;
        optacc[2] += w * kp2;

        // o_pair: pair_z is head-independent -> broadcast w (1 shuffle per target head).
        #pragma unroll
        for (int jh = 0; jh < 8; ++jh) {
            float wj = __shfl(w, (es << 3) + jh);
            opacc[jh][0] += wj * pair4.x;
            opacc[jh][1] += wj * pair4.y;
            opacc[jh][2] += wj * pair4.z;
            opacc[jh][3] += wj * pair4.w;
        }
        ed = ned;
    }

    // reduce across the 8 edge slots (lane bits 3..5)
    #pragma unroll
    for (int delta = 8; delta <= 32; delta <<= 1) {
        ssum += __shfl_xor(ssum, delta);
        #pragma unroll
        for (int c = 0; c < 16; ++c) oacc[c] += __shfl_xor(oacc[c], delta);
        #pragma unroll
        for (int i = 0; i < 3; ++i) optacc[i] += __shfl_xor(optacc[i], delta);
        #pragma unroll
        for (int j = 0; j < 8; ++j)
            #pragma unroll
            for (int c = 0; c < 4; ++c) opacc[j][c] += __shfl_xor(opacc[j][c], delta);
    }

    // Per-head denominators for o_pair (opacc[jh] used head jh's weights).
    float invj[8];
    #pragma unroll
    for (int jh = 0; jh < 8; ++jh)
        invj[jh] = 1.f / (__shfl(ssum, jh) + 1e-16f);

    if (es == 0) {
        float inv = 1.f / (ssum + 1e-16f);
        float* f = feats + (size_t)s * 416;
        // o -> f[0:128]
        #pragma unroll
        for (int c = 0; c < 16; c += 4) {
            float4 v = make_float4(oacc[c] * inv, oacc[c + 1] * inv, oacc[c + 2] * inv, oacc[c + 3] * inv);
            *(float4*)(&f[h * 16 + c]) = v;
        }
        // o_pt rotate back + norm -> f[128:160] (R,T already in registers)
        float v0 = optacc[0] * inv - T0;
        float v1 = optacc[1] * inv - T1;
        float v2 = optacc[2] * inv - T2;
        float r0 = R0 * v0 + R3 * v1 + R6 * v2;
        float r1 = R1 * v0 + R4 * v1 + R7 * v2;
        float r2 = R2 * v0 + R5 * v1 + R8 * v2;
        f[128 + h] = r0;
        f[136 + h] = r1;
        f[144 + h] = r2;
        f[152 + h] = sqrtf(r0 * r0 + r1 * r1 + r2 * r2 + 1e-8f);
        // o_pair -> f[160:416]
        #pragma unroll
        for (int jh = 0; jh < 8; ++jh) {
            float4 v = make_float4(opacc[jh][0] * invj[jh], opacc[jh][1] * invj[jh],
                                   opacc[jh][2] * invj[jh], opacc[jh][3] * invj[jh]);
            *(float4*)(&f[160 + jh * 32 + h * 4]) = v;
        }
    }
}

// ---------------- host ----------------
extern "C" void kernel_launch(void* const* d_in, const int* in_sizes, int n_in,
                              void* d_out, int out_size, void* d_ws, size_t ws_size,
                              hipStream_t stream)
{
    const float* frame_s = (const float*)d_in[0];
    const float* tfn     = (const float*)d_in[1];
    const float* z       = (const float*)d_in[2];
    const int*   ei      = (const int*)d_in[3];
    const float* mask    = (const float*)d_in[4];
    const float* rot     = (const float*)d_in[5];
    const float* trans   = (const float*)d_in[6];
    const float* Wq      = (const float*)d_in[7];
    const float* bq      = (const float*)d_in[8];
    const float* Wks     = (const float*)d_in[9];
    const float* Wkv     = (const float*)d_in[10];
    const float* Wqp     = (const float*)d_in[11];
    const float* bqp     = (const float*)d_in[12];
    const float* Wb      = (const float*)d_in[13];
    const float* bb      = (const float*)d_in[14];
    const float* Wdz     = (const float*)d_in[15];
    const float* bdz     = (const float*)d_in[16];
    const float* hw      = (const float*)d_in[17];
    const float* Wout    = (const float*)d_in[18];
    const float* bout    = (const float*)d_in[19];
    float* out = (float*)d_out;

    int n = in_sizes[0] / 384;
    int E = in_sizes[3] / 2;
    const int* dstA = ei;        // edge_index[0]
    const int* srcA = ei + E;    // edge_index[1]

    float* ws = (float*)d_ws;
    size_t p = 0;
    auto alloc = [&](size_t elems) -> float* {
        float* r = ws + p;
        p += (elems + 15) & ~((size_t)15);
        return r;
    };
    float* qqpbuf = alloc((size_t)n * 320);   // [q | qp_raw]
    float* kbuf   = alloc((size_t)n * 128);
    float* kpts   = alloc((size_t)n * 24);
    float* feats  = alloc((size_t)n * 416);
    float* bpair  = alloc((size_t)E * 40);    // edge order, sequential write
    float* wqqpT  = alloc(320 * 384);
    float* bqqp   = alloc(320);
    float* wcatT  = alloc(40 * 128);
    float* bcat   = alloc(64);
    float* wksT   = alloc(128 * 128);
    float* woutT  = alloc(384 * 416);
    int*  cnt   = (int*)alloc((size_t)n);
    int*  off   = (int*)alloc((size_t)n);
    int*  cur   = (int*)alloc((size_t)n);
    int2* einfo = (int2*)alloc((size_t)E * 2);   // fused (e, dst) records, CSR order

    hipMemsetAsync(cnt, 0, (size_t)n * sizeof(int), stream);

    int nb_cnt = (E + 255) / 256;
    prep_count_kernel<<<nb_cnt + 512, 256, 0, stream>>>(
        Wq, bq, Wqp, bqp, Wb, bb, Wdz, bdz, Wks, Wout,
        wqqpT, bqqp, wcatT, bcat, wksT, woutT,
        srcA, cnt, E, nb_cnt);

    scan_kernel<<<1, 1024, 0, stream>>>(cnt, off, cur, n);

    // mega: bpair stream + qqp GEMM + k GEMM + kpts + fill, one launch
    int nb_bp    = 2048;                       // grid-stride strips
    int nb_qqp_x = (n + 127) / 128;
    int nb_qqp   = nb_qqp_x * 3;               // N=320 -> 3 tiles of 128
    int nb_k     = (n + 127) / 128;
    int nb_kpts  = (n * 24 + 255) / 256;
    int nb_fill  = (E + 255) / 256;
    int nb_total = nb_bp + nb_qqp + nb_k + nb_kpts + nb_fill;
    mega_kernel<<<nb_total, 256, 0, stream>>>(
        z, wcatT, bcat, bpair, E,
        frame_s, wqqpT, bqqp, qqpbuf, n,
        tfn, wksT, kbuf,
        Wkv, kpts,
        srcA, dstA, cur, einfo,
        nb_bp, nb_qqp_x, nb_qqp, nb_k, nb_kpts);

    attn_kernel<<<(n + 3) / 4, 256, 0, stream>>>(off, cnt, einfo,
                                                 qqpbuf, kbuf, kpts, bpair, mask, hw,
                                                 rot, trans, feats, n);

    {   // out = feats @ Wout + bout
        dim3 g((n + 127) / 128, 3);
        gemm_mfma<4><<<g, 256, 0, stream>>>(feats, 416, woutT, 416, bout, out, 384, n, 384, 416);
    }
    (void)n_in; (void)out_size; (void)ws_size;
}